// Round 5
// baseline (1276.089 us; speedup 1.0000x reference)
//
#include <hip/hip_runtime.h>

#define NN 10000
#define NE 160000
#define NG 64
#define NT 5
#define NF 75
#define NL 4
#define LOG17 2.8332133f  /* log(17.0) */
#define ROWB 384          /* bf16 B row stride (375 used) */
#define WCN 896           /* Wcat cols: B 0..374 | base 384..758 | y0 768..842 | pad */

__device__ __forceinline__ unsigned short f2bf(float x){
  unsigned u = __float_as_uint(x);
  unsigned r = (u + 0x7FFFu + ((u >> 16) & 1u)) >> 16;
  return (unsigned short)r;
}

// ---------------------------------------------------------------- setup
__global__ __launch_bounds__(256) void k_init_h(const float* __restrict__ x,
    const float* __restrict__ W, const float* __restrict__ b, float* __restrict__ h){
  int i = blockIdx.x*256 + threadIdx.x;
  if (i >= NN*NF) return;
  int n = i / NF, f = i - n*NF;
  h[i] = x[2*n]*W[f] + x[2*n+1]*W[NF+f] + b[f];
}

__global__ __launch_bounds__(256) void k_count(const int* __restrict__ ei, int* __restrict__ cnt){
  int e = blockIdx.x*256 + threadIdx.x;
  if (e < NE) atomicAdd(&cnt[ei[NE + e]], 1);   // row 1 = dst
}

__global__ __launch_bounds__(1024) void k_scan(const int* __restrict__ cnt,
    int* __restrict__ off, int* __restrict__ cur){
  __shared__ int buf[1024];
  __shared__ int carry;
  int tid = threadIdx.x;
  if (tid == 0) carry = 0;
  __syncthreads();
  for (int base = 0; base < NN; base += 1024){
    int i = base + tid;
    int v = (i < NN) ? cnt[i] : 0;
    buf[tid] = v;
    __syncthreads();
    for (int d = 1; d < 1024; d <<= 1){
      int t = (tid >= d) ? buf[tid - d] : 0;
      __syncthreads();
      buf[tid] += t;
      __syncthreads();
    }
    int c = carry;
    if (i < NN){ int ex = c + buf[tid] - v; off[i] = ex; cur[i] = ex; }
    int tot = buf[1023];
    __syncthreads();
    if (tid == 0) carry = c + tot;
    __syncthreads();
  }
  if (tid == 0) off[NN] = NE;
}

__global__ __launch_bounds__(256) void k_scatter(const int* __restrict__ ei,
    int* __restrict__ cur, int* __restrict__ csr){
  int e = blockIdx.x*256 + threadIdx.x;
  if (e < NE){
    int d = ei[NE + e];
    int p = atomicAdd(&cur[d], 1);
    csr[p] = ei[e];   // src node
  }
}

// Wcat[l][75][896]
__global__ __launch_bounds__(256) void k_buildWcat(const float* __restrict__ preW,
    const float* __restrict__ postW, float* __restrict__ Wcat){
  int idx = blockIdx.x*256 + threadIdx.x;
  if (idx >= NL*75*WCN) return;
  int l = idx / (75*WCN);
  int rem = idx - l*75*WCN;
  int c = rem / WCN, j = rem - c*WCN;
  float v = 0.f;
  if (j < 375){
    int t = j/75, f = j - t*75;
    v = preW[(size_t)((l*NT + t)*150 + 75 + c)*75 + f];
  } else if (j >= 384 && j < 759){
    int jj = j - 384; int t = jj/75, f = jj - t*75;
    v = preW[(size_t)((l*NT + t)*150 + c)*75 + f];
  } else if (j >= 768 && j < 843){
    int jj = j - 768; int t = jj/15, f2 = jj - t*15;
    v = postW[(size_t)((l*NT + t)*975 + c)*15 + f2];
  }
  Wcat[idx] = v;
}

// W45[l][t][300][64] f32: col = 4*(f48/3) + f48%3 ; col%4==3 -> 0
__global__ __launch_bounds__(256) void k_buildW45(const float* __restrict__ postW,
    float* __restrict__ W45){
  int idx = blockIdx.x*256 + threadIdx.x;
  if (idx >= NL*NT*300*64) return;
  int l = idx / (NT*300*64);
  int rem = idx - l*NT*300*64;
  int t = rem / (300*64);
  int rem2 = rem - t*300*64;
  int c = rem2 / 64, col = rem2 - c*64;
  int g3 = col >> 2, e = col & 3;
  float v = 0.f;
  if (e < 3){
    int f48 = g3*3 + e;             // [0,48)
    int g = f48/15, f2 = f48 - g*15;
    if (g < 3)
      v = postW[(size_t)((l*NT + t)*975 + 75 + g*300 + c)*15 + f2];
  }
  W45[idx] = v;
}

// ------ GEMM1: [B(bf16) | base(+preb) | y0] = src(BN?) @ Wcat.  M=10000,K=75
__global__ __launch_bounds__(256) void k_gemm1(const float* __restrict__ src,
    const float* __restrict__ Wcat, const float* __restrict__ preb,
    const float* __restrict__ bnSp, const float* __restrict__ sc,
    const float* __restrict__ bb, int use_bn,
    unsigned short* __restrict__ out1b, float* __restrict__ baseb,
    float* __restrict__ z, int l){
  __shared__ float As[75][68];
  __shared__ float Ws[75][128];
  int tid = threadIdx.x;
  int bid = blockIdx.x;
  int nt = bid / 7, jt = bid - nt*7;
  int n0 = nt*64, j0 = jt*128;

  for (int idx = tid; idx < 64*75; idx += 256){
    int i = idx/75, c = idx - i*75;
    float v = (n0 + i < NN) ? src[(size_t)n0*75 + idx] : 0.f;
    if (use_bn){
      float mu = bnSp[c] * (1.f/NN);
      float var = bnSp[80 + c] * (1.f/NN) - mu*mu;
      v = fmaxf((v - mu) / sqrtf(var + 1e-5f) * sc[c] + bb[c], 0.f);
    }
    As[c][i] = v;
  }
  const float* wg = Wcat + (size_t)l*75*WCN;
  for (int idx = tid; idx < 75*128; idx += 256){
    int c = idx >> 7, j = idx & 127;
    Ws[c][j] = wg[(size_t)c*WCN + j0 + j];
  }
  __syncthreads();

  int jj = tid >> 4, n4 = tid & 15;
  float acc[4][8];
  #pragma unroll
  for (int i = 0; i < 4; ++i)
    #pragma unroll
    for (int j = 0; j < 8; ++j) acc[i][j] = 0.f;

  for (int c = 0; c < 75; ++c){
    float4 a = *reinterpret_cast<const float4*>(&As[c][n4*4]);
    float4 w0 = *reinterpret_cast<const float4*>(&Ws[c][jj*8]);
    float4 w1 = *reinterpret_cast<const float4*>(&Ws[c][jj*8 + 4]);
    float av[4] = {a.x, a.y, a.z, a.w};
    float wv[8] = {w0.x, w0.y, w0.z, w0.w, w1.x, w1.y, w1.z, w1.w};
    #pragma unroll
    for (int i = 0; i < 4; ++i)
      #pragma unroll
      for (int j = 0; j < 8; ++j) acc[i][j] += av[i]*wv[j];
  }

  #pragma unroll
  for (int i = 0; i < 4; ++i){
    int n = n0 + n4*4 + i;
    if (n >= NN) continue;
    #pragma unroll
    for (int j = 0; j < 8; ++j){
      int col = j0 + jj*8 + j;
      float v = acc[i][j];
      if (col < 375){
        out1b[(size_t)n*ROWB + col] = f2bf(v);
      } else if (col >= 384 && col < 759){
        baseb[(size_t)n*384 + (col - 384)] = v + preb[l*375 + (col - 384)];
      } else if (col >= 768 && col < 843){
        z[(size_t)n*75 + (col - 768)] = v;
      }
    }
  }
}

// ---- fused gather(bf16) + 5-tower post-GEMM + scalers + lin + BN-sums
// block = 8 nodes x 16 feat-lanes x 2 edge-slots = 256 threads. grid = NN/8.
__device__ __forceinline__ int swz(int row, int col){ return col ^ ((row >> 3) & 7); }

__global__ __launch_bounds__(256, 3) void k_aggpost(
    const unsigned short* __restrict__ out1b, const float* __restrict__ baseb,
    const float* __restrict__ z,
    const int* __restrict__ off, const int* __restrict__ csr,
    const float* __restrict__ W45, const float* __restrict__ postb,
    const float* __restrict__ linW, const float* __restrict__ linb,
    float* __restrict__ out2, float* __restrict__ bnS1, int l){
  __shared__ float As[300][12];     // swizzled cols; reused as red1/red2 in lin phase
  __shared__ float part[2][48][10];
  __shared__ float zmid[8][78];
  __shared__ float dln[8];
  int tid = threadIdx.x;
  int n0 = blockIdx.x * 8;
  int nl = tid >> 5, rs = tid & 31, r = rs >> 1, slot = rs & 1;
  int n = n0 + nl;                  // NN % 8 == 0 -> always valid

  // ---------- gather-aggregate: each slot takes every other edge
  float s[24], ss[24], mn[24], mx[24];
  #pragma unroll
  for (int j = 0; j < 24; ++j){ s[j]=0.f; ss[j]=0.f; mn[j]=3.4e38f; mx[j]=-3.4e38f; }

#define ST(v,J){ float _v=(v); s[J]+=_v; ss[J]+=_v*_v; mn[J]=fminf(mn[J],_v); mx[J]=fmaxf(mx[J],_v); }
#define PROC(X,J){ \
  ST(__uint_as_float((X).x<<16), J)   ST(__uint_as_float((X).x&0xFFFF0000u), J+1) \
  ST(__uint_as_float((X).y<<16), J+2) ST(__uint_as_float((X).y&0xFFFF0000u), J+3) \
  ST(__uint_as_float((X).z<<16), J+4) ST(__uint_as_float((X).z&0xFFFF0000u), J+5) \
  ST(__uint_as_float((X).w<<16), J+6) ST(__uint_as_float((X).w&0xFFFF0000u), J+7) }

  int e0 = off[n], e1 = off[n+1];
  int deg = e1 - e0;
  float d = (float)(deg > 0 ? deg : 1);
  {
    size_t roff = (size_t)r*24;
    int k = e0 + slot;
    for (; k + 2 < e1; k += 4){
      const uint4* p0 = reinterpret_cast<const uint4*>(out1b + (size_t)csr[k]*ROWB + roff);
      const uint4* p1 = reinterpret_cast<const uint4*>(out1b + (size_t)csr[k+2]*ROWB + roff);
      uint4 x0 = p0[0], x1 = p0[1], x2 = p0[2];
      uint4 y0 = p1[0], y1 = p1[1], y2 = p1[2];
      PROC(x0,0) PROC(x1,8) PROC(x2,16)
      PROC(y0,0) PROC(y1,8) PROC(y2,16)
    }
    if (k < e1){
      const uint4* p0 = reinterpret_cast<const uint4*>(out1b + (size_t)csr[k]*ROWB + roff);
      uint4 x0 = p0[0], x1 = p0[1], x2 = p0[2];
      PROC(x0,0) PROC(x1,8) PROC(x2,16)
    }
  }
#undef PROC
#undef ST

  // combine the two slots (lane-adjacent) — all lanes end up with totals
  #pragma unroll
  for (int j = 0; j < 24; ++j){
    s[j]  += __shfl_xor(s[j], 1);
    ss[j] += __shfl_xor(ss[j], 1);
    mn[j]  = fminf(mn[j], __shfl_xor(mn[j], 1));
    mx[j]  = fmaxf(mx[j], __shfl_xor(mx[j], 1));
  }

  if (deg > 0){
    #pragma unroll
    for (int j = 0; j < 24; ++j){
      int f = r*24 + j;
      if (f < 375){
        float bs = baseb[(size_t)n*384 + f];
        float mb = s[j] / d;
        float var = ss[j] / d - mb*mb;
        s[j]  = bs + mb;
        ss[j] = sqrtf(fmaxf(var, 0.f) + 1e-5f);
        mn[j] = bs + mn[j];
        mx[j] = bs + mx[j];
      }
    }
  } else {
    #pragma unroll
    for (int j = 0; j < 24; ++j){ s[j]=0.f; ss[j]=sqrtf(1e-5f); mn[j]=0.f; mx[j]=0.f; }
  }
  if (rs == 0) dln[nl] = d;

  // ---------- per-tower: stage As (swizzled), GEMM K=300 (split 2x150), epilogue
  int gq = tid & 7;                 // node for GEMM
  int fo = (tid >> 3) & 15;         // output group (3 outputs)
  int kh = tid >> 7;                // K-half
  for (int t = 0; t < NT; ++t){
    if (slot == 0){
      #pragma unroll
      for (int j = 0; j < 24; ++j){
        int f = r*24 + j;
        int u = f - t*75;
        if (f < 375 && u >= 0 && u < 75){
          As[u][swz(u,nl)] = s[j];
          As[75+u][swz(75+u,nl)] = mn[j];
          As[150+u][swz(150+u,nl)] = mx[j];
          As[225+u][swz(225+u,nl)] = ss[j];
        }
      }
    }
    __syncthreads();
    float a0 = 0.f, a1 = 0.f, a2 = 0.f;
    const float4* wp = reinterpret_cast<const float4*>(W45 + (size_t)((l*NT + t)*300)*64);
    int cbeg = kh*150;
    #pragma unroll 5
    for (int cc = cbeg; cc < cbeg + 150; ++cc){
      float a = As[cc][swz(cc,gq)];
      float4 w = wp[cc*16 + fo];
      a0 += a*w.x; a1 += a*w.y; a2 += a*w.z;
    }
    part[kh][fo*3+0][gq] = a0; part[kh][fo*3+1][gq] = a1; part[kh][fo*3+2][gq] = a2;
    __syncthreads();
    if (tid < 120){
      int nl2 = tid / 15, f2 = tid - nl2*15;
      int nn = n0 + nl2;
      float dd = dln[nl2];
      float logd = logf(dd + 1.f);
      float amp = logd * (1.f/LOG17), att = LOG17 / logd;
      float g0 = part[0][f2][nl2]    + part[1][f2][nl2];
      float g1 = part[0][15+f2][nl2] + part[1][15+f2][nl2];
      float g2 = part[0][30+f2][nl2] + part[1][30+f2][nl2];
      zmid[nl2][t*15+f2] = z[(size_t)nn*75 + t*15+f2] + g0 + amp*g1 + att*g2
                           + postb[(l*NT+t)*15 + f2];
    }
    // safe: next As staging writes only As; part written next only after the
    // post-staging __syncthreads, which epilogue threads also pass.
  }
  __syncthreads();

  // ---------- lin: zmid @ linW + linb, with BN partial sums
  float* red1 = &As[0][0];
  float* red2 = red1 + 75*10;
  if (tid < 120){
    int lnl = tid & 7, oo = tid >> 3;     // oo in [0,15)
    int o0 = oo*5;
    float lacc[5] = {0.f,0.f,0.f,0.f,0.f};
    const float* lw = linW + (size_t)l*5625;
    for (int c = 0; c < 75; ++c){
      float a = zmid[lnl][c];
      #pragma unroll
      for (int k = 0; k < 5; ++k) lacc[k] += a * lw[c*75 + o0 + k];
    }
    int nn = n0 + lnl;
    #pragma unroll
    for (int k = 0; k < 5; ++k){
      float v = lacc[k] + linb[l*75 + o0 + k];
      out2[(size_t)nn*75 + o0 + k] = v;
      red1[(o0+k)*10 + lnl] = v;
      red2[(o0+k)*10 + lnl] = v*v;
    }
  }
  __syncthreads();
  if (tid < 75){
    float b1 = 0.f, b2 = 0.f;
    #pragma unroll
    for (int jj = 0; jj < 8; ++jj){ b1 += red1[tid*10+jj]; b2 += red2[tid*10+jj]; }
    atomicAdd(&bnS1[tid], b1);
    atomicAdd(&bnS1[80+tid], b2);
  }
}

// -------------------------------- final BN+ReLU fused with global_add_pool
__global__ __launch_bounds__(256) void k_bnpool(const float* __restrict__ out2,
    const float* __restrict__ bnSp, const float* __restrict__ sc,
    const float* __restrict__ bb, const int* __restrict__ batch,
    float* __restrict__ pooled){
  int i = blockIdx.x*256 + threadIdx.x;
  if (i >= NN*75) return;
  int n = i / 75, f = i - n*75;
  float mu = bnSp[f] * (1.f/NN);
  float var = bnSp[80 + f] * (1.f/NN) - mu*mu;
  float v = fmaxf((out2[i] - mu) / sqrtf(var + 1e-5f) * sc[f] + bb[f], 0.f);
  atomicAdd(&pooled[batch[n]*75 + f], v);
}

__global__ __launch_bounds__(256) void k_head(const float* __restrict__ pooled,
    const float* __restrict__ W1, const float* __restrict__ b1,
    const float* __restrict__ W2, const float* __restrict__ b2,
    const float* __restrict__ W3, const float* __restrict__ b3,
    float* __restrict__ out){
  __shared__ float pl[64*75];
  __shared__ float w1[75*50];
  __shared__ float z1[64*50];
  __shared__ float w2[50*25];
  __shared__ float z2[64*25];
  __shared__ float w3[25];
  __shared__ float bb1[50], bb2[25];
  int tid = threadIdx.x;
  for (int i = tid; i < 64*75; i += 256) pl[i] = pooled[i];
  for (int i = tid; i < 75*50; i += 256) w1[i] = W1[i];
  for (int i = tid; i < 50*25; i += 256) w2[i] = W2[i];
  if (tid < 25) w3[tid] = W3[tid];
  if (tid < 50) bb1[tid] = b1[tid];
  if (tid < 25) bb2[tid] = b2[tid];
  __syncthreads();
  for (int o = tid; o < 64*50; o += 256){
    int g = o / 50, j = o - g*50;
    float acc = bb1[j];
    for (int c = 0; c < 75; ++c) acc += pl[g*75 + c] * w1[c*50 + j];
    z1[o] = fmaxf(acc, 0.f);
  }
  __syncthreads();
  for (int o = tid; o < 64*25; o += 256){
    int g = o / 25, j = o - g*25;
    float acc = bb2[j];
    for (int c = 0; c < 50; ++c) acc += z1[g*50 + c] * w2[c*25 + j];
    z2[o] = fmaxf(acc, 0.f);
  }
  __syncthreads();
  if (tid < 64){
    float acc = b3[0];
    for (int c = 0; c < 25; ++c) acc += z2[tid*25 + c] * w3[c];
    out[tid] = acc;
  }
}

// ---------------------------------------------------------------- launcher
extern "C" void kernel_launch(void* const* d_in, const int* in_sizes, int n_in,
                              void* d_out, int out_size, void* d_ws, size_t ws_size,
                              hipStream_t stream){
  const float* x     = (const float*)d_in[0];
  const int*   ei    = (const int*)  d_in[1];
  const int*   batch = (const int*)  d_in[2];
  const float* plW   = (const float*)d_in[3];
  const float* plb   = (const float*)d_in[4];
  const float* preW  = (const float*)d_in[5];
  const float* preb  = (const float*)d_in[6];
  const float* postW = (const float*)d_in[7];
  const float* postb = (const float*)d_in[8];
  const float* linW  = (const float*)d_in[9];
  const float* linb  = (const float*)d_in[10];
  const float* bns   = (const float*)d_in[11];
  const float* bnb   = (const float*)d_in[12];
  const float* W1    = (const float*)d_in[13];
  const float* b1    = (const float*)d_in[14];
  const float* W2    = (const float*)d_in[15];
  const float* b2    = (const float*)d_in[16];
  const float* W3    = (const float*)d_in[17];
  const float* b3    = (const float*)d_in[18];
  float* out = (float*)d_out;

  // workspace layout (~32 MB)
  float* h0    = (float*)d_ws;                     // 750000
  float* out2v = h0 + 750000;                      // 750000
  float* zv    = out2v + 750000;                   // 750000
  float* baseb = zv + 750000;                      // NN*384
  float* Wcat  = baseb + (size_t)NN*384;           // 4*75*896
  float* W45   = Wcat + NL*75*WCN;                 // 4*5*300*64
  float* pooled= W45 + NL*NT*300*64;               // 4800
  float* bnS   = pooled + 4800;                    // 4*160
  unsigned short* out1b = (unsigned short*)(bnS + NL*160);  // NN*384 ushorts (16B-aligned)
  int* cnt = (int*)(out1b + (size_t)NN*ROWB);
  int* off = cnt + NN;
  int* cur = off + NN + 1;
  int* csr = cur + NN;

  hipMemsetAsync(cnt, 0, NN*sizeof(int), stream);
  hipMemsetAsync(bnS, 0, NL*160*sizeof(float), stream);
  hipMemsetAsync(pooled, 0, 4800*sizeof(float), stream);
  k_init_h<<<(NN*NF + 255)/256, 256, 0, stream>>>(x, plW, plb, h0);
  k_count<<<(NE + 255)/256, 256, 0, stream>>>(ei, cnt);
  k_scan<<<1, 1024, 0, stream>>>(cnt, off, cur);
  k_scatter<<<(NE + 255)/256, 256, 0, stream>>>(ei, cur, csr);
  k_buildWcat<<<(NL*75*WCN + 255)/256, 256, 0, stream>>>(preW, postW, Wcat);
  k_buildW45<<<(NL*NT*300*64 + 255)/256, 256, 0, stream>>>(postW, W45);

  for (int l = 0; l < NL; ++l){
    const float* src = (l == 0) ? h0 : out2v;
    const float* bnSp = bnS + (l > 0 ? (l-1)*160 : 0);
    const float* sc = bns + (l > 0 ? (l-1)*75 : 0);
    const float* bb = bnb + (l > 0 ? (l-1)*75 : 0);
    k_gemm1<<<157*7, 256, 0, stream>>>(src, Wcat, preb, bnSp, sc, bb, (l > 0),
                                       out1b, baseb, zv, l);
    k_aggpost<<<NN/8, 256, 0, stream>>>(out1b, baseb, zv, off, csr, W45, postb,
                                        linW, linb, out2v, bnS + l*160, l);
  }

  k_bnpool<<<(NN*NF + 255)/256, 256, 0, stream>>>(out2v, bnS + 3*160,
                                                  bns + 3*75, bnb + 3*75, batch, pooled);
  k_head<<<1, 256, 0, stream>>>(pooled, W1, b1, W2, b2, W3, b3, out);
}

// Round 6
// 1205.878 us; speedup vs baseline: 1.0582x; 1.0582x over previous
//
#include <hip/hip_runtime.h>

#define NN 10000
#define NE 160000
#define NG 64
#define NT 5
#define NF 75
#define NL 4
#define LOG17 2.8332133f  /* log(17.0) */
#define ROWB 384          /* bf16 B row stride (375 used, pads zeroed once) */
#define WCN 896           /* Wcat cols: B 0..374 | base 384..758 | y0 768..842 | pad */

__device__ __forceinline__ unsigned short f2bf(float x){
  unsigned u = __float_as_uint(x);
  unsigned r = (u + 0x7FFFu + ((u >> 16) & 1u)) >> 16;
  return (unsigned short)r;
}

// ---------------------------------------------------------------- setup
__global__ __launch_bounds__(256) void k_init_h(const float* __restrict__ x,
    const float* __restrict__ W, const float* __restrict__ b, float* __restrict__ h){
  int i = blockIdx.x*256 + threadIdx.x;
  if (i >= NN*NF) return;
  int n = i / NF, f = i - n*NF;
  h[i] = x[2*n]*W[f] + x[2*n+1]*W[NF+f] + b[f];
}

__global__ __launch_bounds__(256) void k_count(const int* __restrict__ ei, int* __restrict__ cnt){
  int e = blockIdx.x*256 + threadIdx.x;
  if (e < NE) atomicAdd(&cnt[ei[NE + e]], 1);   // row 1 = dst
}

__global__ __launch_bounds__(1024) void k_scan(const int* __restrict__ cnt,
    int* __restrict__ off, int* __restrict__ cur){
  __shared__ int buf[1024];
  __shared__ int carry;
  int tid = threadIdx.x;
  if (tid == 0) carry = 0;
  __syncthreads();
  for (int base = 0; base < NN; base += 1024){
    int i = base + tid;
    int v = (i < NN) ? cnt[i] : 0;
    buf[tid] = v;
    __syncthreads();
    for (int d = 1; d < 1024; d <<= 1){
      int t = (tid >= d) ? buf[tid - d] : 0;
      __syncthreads();
      buf[tid] += t;
      __syncthreads();
    }
    int c = carry;
    if (i < NN){ int ex = c + buf[tid] - v; off[i] = ex; cur[i] = ex; }
    int tot = buf[1023];
    __syncthreads();
    if (tid == 0) carry = c + tot;
    __syncthreads();
  }
  if (tid == 0) off[NN] = NE;
}

__global__ __launch_bounds__(256) void k_scatter(const int* __restrict__ ei,
    int* __restrict__ cur, int* __restrict__ csr){
  int e = blockIdx.x*256 + threadIdx.x;
  if (e < NE){
    int d = ei[NE + e];
    int p = atomicAdd(&cur[d], 1);
    csr[p] = ei[e];   // src node
  }
}

// Wcat[l][75][896]
__global__ __launch_bounds__(256) void k_buildWcat(const float* __restrict__ preW,
    const float* __restrict__ postW, float* __restrict__ Wcat){
  int idx = blockIdx.x*256 + threadIdx.x;
  if (idx >= NL*75*WCN) return;
  int l = idx / (75*WCN);
  int rem = idx - l*75*WCN;
  int c = rem / WCN, j = rem - c*WCN;
  float v = 0.f;
  if (j < 375){
    int t = j/75, f = j - t*75;
    v = preW[(size_t)((l*NT + t)*150 + 75 + c)*75 + f];
  } else if (j >= 384 && j < 759){
    int jj = j - 384; int t = jj/75, f = jj - t*75;
    v = preW[(size_t)((l*NT + t)*150 + c)*75 + f];
  } else if (j >= 768 && j < 843){
    int jj = j - 768; int t = jj/15, f2 = jj - t*15;
    v = postW[(size_t)((l*NT + t)*975 + c)*15 + f2];
  }
  Wcat[idx] = v;
}

// W45[l][t][300][64] f32: col = 4*(f48/3) + f48%3 ; col%4==3 -> 0
__global__ __launch_bounds__(256) void k_buildW45(const float* __restrict__ postW,
    float* __restrict__ W45){
  int idx = blockIdx.x*256 + threadIdx.x;
  if (idx >= NL*NT*300*64) return;
  int l = idx / (NT*300*64);
  int rem = idx - l*NT*300*64;
  int t = rem / (300*64);
  int rem2 = rem - t*300*64;
  int c = rem2 / 64, col = rem2 - c*64;
  int g3 = col >> 2, e = col & 3;
  float v = 0.f;
  if (e < 3){
    int f48 = g3*3 + e;             // [0,48)
    int g = f48/15, f2 = f48 - g*15;
    if (g < 3)
      v = postW[(size_t)((l*NT + t)*975 + 75 + g*300 + c)*15 + f2];
  }
  W45[idx] = v;
}

// ------ GEMM1: [B(bf16) | base(+preb) | y0] = src(BN?) @ Wcat.  M=10000,K=75
__global__ __launch_bounds__(256) void k_gemm1(const float* __restrict__ src,
    const float* __restrict__ Wcat, const float* __restrict__ preb,
    const float* __restrict__ bnSp, const float* __restrict__ sc,
    const float* __restrict__ bb, int use_bn,
    unsigned short* __restrict__ out1b, float* __restrict__ baseb,
    float* __restrict__ z, int l){
  __shared__ float As[75][68];
  __shared__ float Ws[75][128];
  int tid = threadIdx.x;
  int bid = blockIdx.x;
  int nt = bid / 7, jt = bid - nt*7;
  int n0 = nt*64, j0 = jt*128;

  for (int idx = tid; idx < 64*75; idx += 256){
    int i = idx/75, c = idx - i*75;
    float v = (n0 + i < NN) ? src[(size_t)n0*75 + idx] : 0.f;
    if (use_bn){
      float mu = bnSp[c] * (1.f/NN);
      float var = bnSp[80 + c] * (1.f/NN) - mu*mu;
      v = fmaxf((v - mu) / sqrtf(var + 1e-5f) * sc[c] + bb[c], 0.f);
    }
    As[c][i] = v;
  }
  const float* wg = Wcat + (size_t)l*75*WCN;
  for (int idx = tid; idx < 75*128; idx += 256){
    int c = idx >> 7, j = idx & 127;
    Ws[c][j] = wg[(size_t)c*WCN + j0 + j];
  }
  __syncthreads();

  int jj = tid >> 4, n4 = tid & 15;
  float acc[4][8];
  #pragma unroll
  for (int i = 0; i < 4; ++i)
    #pragma unroll
    for (int j = 0; j < 8; ++j) acc[i][j] = 0.f;

  for (int c = 0; c < 75; ++c){
    float4 a = *reinterpret_cast<const float4*>(&As[c][n4*4]);
    float4 w0 = *reinterpret_cast<const float4*>(&Ws[c][jj*8]);
    float4 w1 = *reinterpret_cast<const float4*>(&Ws[c][jj*8 + 4]);
    float av[4] = {a.x, a.y, a.z, a.w};
    float wv[8] = {w0.x, w0.y, w0.z, w0.w, w1.x, w1.y, w1.z, w1.w};
    #pragma unroll
    for (int i = 0; i < 4; ++i)
      #pragma unroll
      for (int j = 0; j < 8; ++j) acc[i][j] += av[i]*wv[j];
  }

  #pragma unroll
  for (int i = 0; i < 4; ++i){
    int n = n0 + n4*4 + i;
    if (n >= NN) continue;
    #pragma unroll
    for (int j = 0; j < 8; ++j){
      int col = j0 + jj*8 + j;
      float v = acc[i][j];
      if (col < 375){
        out1b[(size_t)n*ROWB + col] = f2bf(v);
      } else if (col >= 384 && col < 759){
        baseb[(size_t)n*384 + (col - 384)] = v + preb[l*375 + (col - 384)];
      } else if (col >= 768 && col < 843){
        z[(size_t)n*75 + (col - 768)] = v;
      }
    }
  }
}

// ---- fused gather(bf16) + 5-tower post-GEMM + scalers + lin + BN-sums
// block = 8 nodes x 32 lanes = 256 threads; lane owns 12 feats (48 stat regs,
// no spill). grid = NN/8.
__device__ __forceinline__ int swz(int row, int col){ return col ^ ((row >> 3) & 7); }

__global__ __launch_bounds__(256) void k_aggpost(
    const unsigned short* __restrict__ out1b, const float* __restrict__ baseb,
    const float* __restrict__ z,
    const int* __restrict__ off, const int* __restrict__ csr,
    const float* __restrict__ W45, const float* __restrict__ postb,
    const float* __restrict__ linW, const float* __restrict__ linb,
    float* __restrict__ out2, float* __restrict__ bnS1, int l){
  __shared__ float As[300][12];     // swizzled cols; reused as red1/red2 in lin phase
  __shared__ float part[2][48][10];
  __shared__ float zmid[8][78];
  __shared__ float dln[8];
  int tid = threadIdx.x;
  int n0 = blockIdx.x * 8;
  int nl = tid >> 5, r = tid & 31;
  int n = n0 + nl;                  // NN % 8 == 0 -> always valid

  // ---------- gather-aggregate: 12 feats/lane via 3x uint2 (8B, aligned)
  float s[12], ss[12], mn[12], mx[12];
  #pragma unroll
  for (int j = 0; j < 12; ++j){ s[j]=0.f; ss[j]=0.f; mn[j]=3.4e38f; mx[j]=-3.4e38f; }

#define ST(v,J){ float _v=(v); s[J]+=_v; ss[J]+=_v*_v; mn[J]=fminf(mn[J],_v); mx[J]=fmaxf(mx[J],_v); }
#define PROCU(U,J){ ST(__uint_as_float((U)<<16), J) ST(__uint_as_float((U)&0xFFFF0000u), J+1) }
#define PROC2(X,J){ PROCU((X).x, J) PROCU((X).y, J+2) }

  int e0 = off[n], e1 = off[n+1];
  int deg = e1 - e0;
  float d = (float)(deg > 0 ? deg : 1);
  {
    int fo12 = r*12;                // element offset within 384-elem row
    int k = e0;
    for (; k + 1 < e1; k += 2){
      const uint2* p0 = reinterpret_cast<const uint2*>(out1b + (size_t)csr[k]*ROWB + fo12);
      const uint2* p1 = reinterpret_cast<const uint2*>(out1b + (size_t)csr[k+1]*ROWB + fo12);
      uint2 x0 = p0[0], x1 = p0[1], x2 = p0[2];
      uint2 y0 = p1[0], y1 = p1[1], y2 = p1[2];
      PROC2(x0,0) PROC2(x1,4) PROC2(x2,8)
      PROC2(y0,0) PROC2(y1,4) PROC2(y2,8)
    }
    if (k < e1){
      const uint2* p0 = reinterpret_cast<const uint2*>(out1b + (size_t)csr[k]*ROWB + fo12);
      uint2 x0 = p0[0], x1 = p0[1], x2 = p0[2];
      PROC2(x0,0) PROC2(x1,4) PROC2(x2,8)
    }
  }
#undef PROC2
#undef PROCU
#undef ST

  if (deg > 0){
    #pragma unroll
    for (int j = 0; j < 12; ++j){
      int f = r*12 + j;
      if (f < 375){
        float bs = baseb[(size_t)n*384 + f];
        float mb = s[j] / d;
        float var = ss[j] / d - mb*mb;
        s[j]  = bs + mb;
        ss[j] = sqrtf(fmaxf(var, 0.f) + 1e-5f);
        mn[j] = bs + mn[j];
        mx[j] = bs + mx[j];
      }
    }
  } else {
    #pragma unroll
    for (int j = 0; j < 12; ++j){ s[j]=0.f; ss[j]=sqrtf(1e-5f); mn[j]=0.f; mx[j]=0.f; }
  }
  if (r == 0) dln[nl] = d;

  // ---------- per-tower: stage As (swizzled), GEMM K=300 (split 2x150), epilogue
  int gq = tid & 7;                 // node for GEMM
  int fo = (tid >> 3) & 15;         // output group (3 outputs)
  int kh = tid >> 7;                // K-half
  for (int t = 0; t < NT; ++t){
    #pragma unroll
    for (int j = 0; j < 12; ++j){
      int f = r*12 + j;
      int u = f - t*75;
      if (f < 375 && u >= 0 && u < 75){
        As[u][swz(u,nl)] = s[j];
        As[75+u][swz(75+u,nl)] = mn[j];
        As[150+u][swz(150+u,nl)] = mx[j];
        As[225+u][swz(225+u,nl)] = ss[j];
      }
    }
    __syncthreads();
    float a0 = 0.f, a1 = 0.f, a2 = 0.f;
    const float4* wp = reinterpret_cast<const float4*>(W45 + (size_t)((l*NT + t)*300)*64);
    int cbeg = kh*150;
    #pragma unroll 5
    for (int cc = cbeg; cc < cbeg + 150; ++cc){
      float a = As[cc][swz(cc,gq)];
      float4 w = wp[cc*16 + fo];
      a0 += a*w.x; a1 += a*w.y; a2 += a*w.z;
    }
    part[kh][fo*3+0][gq] = a0; part[kh][fo*3+1][gq] = a1; part[kh][fo*3+2][gq] = a2;
    __syncthreads();
    if (tid < 120){
      int nl2 = tid / 15, f2 = tid - nl2*15;
      int nn = n0 + nl2;
      float dd = dln[nl2];
      float logd = logf(dd + 1.f);
      float amp = logd * (1.f/LOG17), att = LOG17 / logd;
      float g0 = part[0][f2][nl2]    + part[1][f2][nl2];
      float g1 = part[0][15+f2][nl2] + part[1][15+f2][nl2];
      float g2 = part[0][30+f2][nl2] + part[1][30+f2][nl2];
      zmid[nl2][t*15+f2] = z[(size_t)nn*75 + t*15+f2] + g0 + amp*g1 + att*g2
                           + postb[(l*NT+t)*15 + f2];
    }
    // safe: next As staging writes only As; part is rewritten only after the
    // post-staging __syncthreads, which epilogue threads also pass.
  }
  __syncthreads();

  // ---------- lin: zmid @ linW + linb, with BN partial sums
  float* red1 = &As[0][0];
  float* red2 = red1 + 75*10;
  if (tid < 120){
    int lnl = tid & 7, oo = tid >> 3;     // oo in [0,15)
    int o0 = oo*5;
    float lacc[5] = {0.f,0.f,0.f,0.f,0.f};
    const float* lw = linW + (size_t)l*5625;
    for (int c = 0; c < 75; ++c){
      float a = zmid[lnl][c];
      #pragma unroll
      for (int k = 0; k < 5; ++k) lacc[k] += a * lw[c*75 + o0 + k];
    }
    int nn = n0 + lnl;
    #pragma unroll
    for (int k = 0; k < 5; ++k){
      float v = lacc[k] + linb[l*75 + o0 + k];
      out2[(size_t)nn*75 + o0 + k] = v;
      red1[(o0+k)*10 + lnl] = v;
      red2[(o0+k)*10 + lnl] = v*v;
    }
  }
  __syncthreads();
  if (tid < 75){
    float b1 = 0.f, b2 = 0.f;
    #pragma unroll
    for (int jj = 0; jj < 8; ++jj){ b1 += red1[tid*10+jj]; b2 += red2[tid*10+jj]; }
    atomicAdd(&bnS1[tid], b1);
    atomicAdd(&bnS1[80+tid], b2);
  }
}

// -------------------------------- final BN+ReLU fused with global_add_pool
__global__ __launch_bounds__(256) void k_bnpool(const float* __restrict__ out2,
    const float* __restrict__ bnSp, const float* __restrict__ sc,
    const float* __restrict__ bb, const int* __restrict__ batch,
    float* __restrict__ pooled){
  int i = blockIdx.x*256 + threadIdx.x;
  if (i >= NN*75) return;
  int n = i / 75, f = i - n*75;
  float mu = bnSp[f] * (1.f/NN);
  float var = bnSp[80 + f] * (1.f/NN) - mu*mu;
  float v = fmaxf((out2[i] - mu) / sqrtf(var + 1e-5f) * sc[f] + bb[f], 0.f);
  atomicAdd(&pooled[batch[n]*75 + f], v);
}

__global__ __launch_bounds__(256) void k_head(const float* __restrict__ pooled,
    const float* __restrict__ W1, const float* __restrict__ b1,
    const float* __restrict__ W2, const float* __restrict__ b2,
    const float* __restrict__ W3, const float* __restrict__ b3,
    float* __restrict__ out){
  __shared__ float pl[64*75];
  __shared__ float w1[75*50];
  __shared__ float z1[64*50];
  __shared__ float w2[50*25];
  __shared__ float z2[64*25];
  __shared__ float w3[25];
  __shared__ float bb1[50], bb2[25];
  int tid = threadIdx.x;
  for (int i = tid; i < 64*75; i += 256) pl[i] = pooled[i];
  for (int i = tid; i < 75*50; i += 256) w1[i] = W1[i];
  for (int i = tid; i < 50*25; i += 256) w2[i] = W2[i];
  if (tid < 25) w3[tid] = W3[tid];
  if (tid < 50) bb1[tid] = b1[tid];
  if (tid < 25) bb2[tid] = b2[tid];
  __syncthreads();
  for (int o = tid; o < 64*50; o += 256){
    int g = o / 50, j = o - g*50;
    float acc = bb1[j];
    for (int c = 0; c < 75; ++c) acc += pl[g*75 + c] * w1[c*50 + j];
    z1[o] = fmaxf(acc, 0.f);
  }
  __syncthreads();
  for (int o = tid; o < 64*25; o += 256){
    int g = o / 25, j = o - g*25;
    float acc = bb2[j];
    for (int c = 0; c < 50; ++c) acc += z1[g*50 + c] * w2[c*25 + j];
    z2[o] = fmaxf(acc, 0.f);
  }
  __syncthreads();
  if (tid < 64){
    float acc = b3[0];
    for (int c = 0; c < 25; ++c) acc += z2[tid*25 + c] * w3[c];
    out[tid] = acc;
  }
}

// ---------------------------------------------------------------- launcher
extern "C" void kernel_launch(void* const* d_in, const int* in_sizes, int n_in,
                              void* d_out, int out_size, void* d_ws, size_t ws_size,
                              hipStream_t stream){
  const float* x     = (const float*)d_in[0];
  const int*   ei    = (const int*)  d_in[1];
  const int*   batch = (const int*)  d_in[2];
  const float* plW   = (const float*)d_in[3];
  const float* plb   = (const float*)d_in[4];
  const float* preW  = (const float*)d_in[5];
  const float* preb  = (const float*)d_in[6];
  const float* postW = (const float*)d_in[7];
  const float* postb = (const float*)d_in[8];
  const float* linW  = (const float*)d_in[9];
  const float* linb  = (const float*)d_in[10];
  const float* bns   = (const float*)d_in[11];
  const float* bnb   = (const float*)d_in[12];
  const float* W1    = (const float*)d_in[13];
  const float* b1    = (const float*)d_in[14];
  const float* W2    = (const float*)d_in[15];
  const float* b2    = (const float*)d_in[16];
  const float* W3    = (const float*)d_in[17];
  const float* b3    = (const float*)d_in[18];
  float* out = (float*)d_out;

  // workspace layout (~32 MB)
  float* h0    = (float*)d_ws;                     // 750000
  float* out2v = h0 + 750000;                      // 750000
  float* zv    = out2v + 750000;                   // 750000
  float* baseb = zv + 750000;                      // NN*384
  float* Wcat  = baseb + (size_t)NN*384;           // 4*75*896
  float* W45   = Wcat + NL*75*WCN;                 // 4*5*300*64
  float* pooled= W45 + NL*NT*300*64;               // 4800
  float* bnS   = pooled + 4800;                    // 4*160
  unsigned short* out1b = (unsigned short*)(bnS + NL*160);  // NN*384 ushorts (16B-aligned)
  int* cnt = (int*)(out1b + (size_t)NN*ROWB);
  int* off = cnt + NN;
  int* cur = off + NN + 1;
  int* csr = cur + NN;

  hipMemsetAsync(cnt, 0, NN*sizeof(int), stream);
  hipMemsetAsync(bnS, 0, NL*160*sizeof(float), stream);
  hipMemsetAsync(pooled, 0, 4800*sizeof(float), stream);
  hipMemsetAsync(out1b, 0, (size_t)NN*ROWB*sizeof(unsigned short), stream); // zero pads 375..383
  k_init_h<<<(NN*NF + 255)/256, 256, 0, stream>>>(x, plW, plb, h0);
  k_count<<<(NE + 255)/256, 256, 0, stream>>>(ei, cnt);
  k_scan<<<1, 1024, 0, stream>>>(cnt, off, cur);
  k_scatter<<<(NE + 255)/256, 256, 0, stream>>>(ei, cur, csr);
  k_buildWcat<<<(NL*75*WCN + 255)/256, 256, 0, stream>>>(preW, postW, Wcat);
  k_buildW45<<<(NL*NT*300*64 + 255)/256, 256, 0, stream>>>(postW, W45);

  for (int l = 0; l < NL; ++l){
    const float* src = (l == 0) ? h0 : out2v;
    const float* bnSp = bnS + (l > 0 ? (l-1)*160 : 0);
    const float* sc = bns + (l > 0 ? (l-1)*75 : 0);
    const float* bb = bnb + (l > 0 ? (l-1)*75 : 0);
    k_gemm1<<<157*7, 256, 0, stream>>>(src, Wcat, preb, bnSp, sc, bb, (l > 0),
                                       out1b, baseb, zv, l);
    k_aggpost<<<NN/8, 256, 0, stream>>>(out1b, baseb, zv, off, csr, W45, postb,
                                        linW, linb, out2v, bnS + l*160, l);
  }

  k_bnpool<<<(NN*NF + 255)/256, 256, 0, stream>>>(out2v, bnS + 3*160,
                                                  bns + 3*75, bnb + 3*75, batch, pooled);
  k_head<<<1, 256, 0, stream>>>(pooled, W1, b1, W2, b2, W3, b3, out);
}

// Round 7
// 1074.788 us; speedup vs baseline: 1.1873x; 1.1220x over previous
//
#include <hip/hip_runtime.h>

#define NN 10000
#define NE 160000
#define NG 64
#define NT 5
#define NF 75
#define NL 4
#define LOG17 2.8332133f  /* log(17.0) */
#define ROWB 384          /* bf16 B row stride (375 used, pads zeroed once) */
#define WCN 896           /* Wcat cols: B 0..374 | base 384..758 | y0 768..842 | pad */

__device__ __forceinline__ unsigned short f2bf(float x){
  unsigned u = __float_as_uint(x);
  unsigned r = (u + 0x7FFFu + ((u >> 16) & 1u)) >> 16;
  return (unsigned short)r;
}
__device__ __forceinline__ float blo(unsigned u){ return __uint_as_float(u << 16); }
__device__ __forceinline__ float bhi(unsigned u){ return __uint_as_float(u & 0xFFFF0000u); }

// ---------------------------------------------------------------- setup
__global__ __launch_bounds__(256) void k_init_h(const float* __restrict__ x,
    const float* __restrict__ W, const float* __restrict__ b, float* __restrict__ h){
  int i = blockIdx.x*256 + threadIdx.x;
  if (i >= NN*NF) return;
  int n = i / NF, f = i - n*NF;
  h[i] = x[2*n]*W[f] + x[2*n+1]*W[NF+f] + b[f];
}

__global__ __launch_bounds__(256) void k_count(const int* __restrict__ ei, int* __restrict__ cnt){
  int e = blockIdx.x*256 + threadIdx.x;
  if (e < NE) atomicAdd(&cnt[ei[NE + e]], 1);   // row 1 = dst
}

__global__ __launch_bounds__(1024) void k_scan(const int* __restrict__ cnt,
    int* __restrict__ off, int* __restrict__ cur){
  __shared__ int buf[1024];
  __shared__ int carry;
  int tid = threadIdx.x;
  if (tid == 0) carry = 0;
  __syncthreads();
  for (int base = 0; base < NN; base += 1024){
    int i = base + tid;
    int v = (i < NN) ? cnt[i] : 0;
    buf[tid] = v;
    __syncthreads();
    for (int d = 1; d < 1024; d <<= 1){
      int t = (tid >= d) ? buf[tid - d] : 0;
      __syncthreads();
      buf[tid] += t;
      __syncthreads();
    }
    int c = carry;
    if (i < NN){ int ex = c + buf[tid] - v; off[i] = ex; cur[i] = ex; }
    int tot = buf[1023];
    __syncthreads();
    if (tid == 0) carry = c + tot;
    __syncthreads();
  }
  if (tid == 0) off[NN] = NE;
}

__global__ __launch_bounds__(256) void k_scatter(const int* __restrict__ ei,
    int* __restrict__ cur, int* __restrict__ csr){
  int e = blockIdx.x*256 + threadIdx.x;
  if (e < NE){
    int d = ei[NE + e];
    int p = atomicAdd(&cur[d], 1);
    csr[p] = ei[e];   // src node
  }
}

// Wcat[l][75][896]
__global__ __launch_bounds__(256) void k_buildWcat(const float* __restrict__ preW,
    const float* __restrict__ postW, float* __restrict__ Wcat){
  int idx = blockIdx.x*256 + threadIdx.x;
  if (idx >= NL*75*WCN) return;
  int l = idx / (75*WCN);
  int rem = idx - l*75*WCN;
  int c = rem / WCN, j = rem - c*WCN;
  float v = 0.f;
  if (j < 375){
    int t = j/75, f = j - t*75;
    v = preW[(size_t)((l*NT + t)*150 + 75 + c)*75 + f];
  } else if (j >= 384 && j < 759){
    int jj = j - 384; int t = jj/75, f = jj - t*75;
    v = preW[(size_t)((l*NT + t)*150 + c)*75 + f];
  } else if (j >= 768 && j < 843){
    int jj = j - 768; int t = jj/15, f2 = jj - t*15;
    v = postW[(size_t)((l*NT + t)*975 + c)*15 + f2];
  }
  Wcat[idx] = v;
}

// W45[l][t][300][64] f32: col = 4*(f48/3) + f48%3 ; col%4==3 -> 0
__global__ __launch_bounds__(256) void k_buildW45(const float* __restrict__ postW,
    float* __restrict__ W45){
  int idx = blockIdx.x*256 + threadIdx.x;
  if (idx >= NL*NT*300*64) return;
  int l = idx / (NT*300*64);
  int rem = idx - l*NT*300*64;
  int t = rem / (300*64);
  int rem2 = rem - t*300*64;
  int c = rem2 / 64, col = rem2 - c*64;
  int g3 = col >> 2, e = col & 3;
  float v = 0.f;
  if (e < 3){
    int f48 = g3*3 + e;             // [0,48)
    int g = f48/15, f2 = f48 - g*15;
    if (g < 3)
      v = postW[(size_t)((l*NT + t)*975 + 75 + g*300 + c)*15 + f2];
  }
  W45[idx] = v;
}

// ------ GEMM1: [B(bf16) | base(+preb) | y0] = src(BN?) @ Wcat.  M=10000,K=75
__global__ __launch_bounds__(256) void k_gemm1(const float* __restrict__ src,
    const float* __restrict__ Wcat, const float* __restrict__ preb,
    const float* __restrict__ bnSp, const float* __restrict__ sc,
    const float* __restrict__ bb, int use_bn,
    unsigned short* __restrict__ out1b, float* __restrict__ baseb,
    float* __restrict__ z, int l){
  __shared__ float As[75][68];
  __shared__ float Ws[75][128];
  int tid = threadIdx.x;
  int bid = blockIdx.x;
  int nt = bid / 7, jt = bid - nt*7;
  int n0 = nt*64, j0 = jt*128;

  for (int idx = tid; idx < 64*75; idx += 256){
    int i = idx/75, c = idx - i*75;
    float v = (n0 + i < NN) ? src[(size_t)n0*75 + idx] : 0.f;
    if (use_bn){
      float mu = bnSp[c] * (1.f/NN);
      float var = bnSp[80 + c] * (1.f/NN) - mu*mu;
      v = fmaxf((v - mu) / sqrtf(var + 1e-5f) * sc[c] + bb[c], 0.f);
    }
    As[c][i] = v;
  }
  const float* wg = Wcat + (size_t)l*75*WCN;
  for (int idx = tid; idx < 75*128; idx += 256){
    int c = idx >> 7, j = idx & 127;
    Ws[c][j] = wg[(size_t)c*WCN + j0 + j];
  }
  __syncthreads();

  int jj = tid >> 4, n4 = tid & 15;
  float acc[4][8];
  #pragma unroll
  for (int i = 0; i < 4; ++i)
    #pragma unroll
    for (int j = 0; j < 8; ++j) acc[i][j] = 0.f;

  for (int c = 0; c < 75; ++c){
    float4 a = *reinterpret_cast<const float4*>(&As[c][n4*4]);
    float4 w0 = *reinterpret_cast<const float4*>(&Ws[c][jj*8]);
    float4 w1 = *reinterpret_cast<const float4*>(&Ws[c][jj*8 + 4]);
    float av[4] = {a.x, a.y, a.z, a.w};
    float wv[8] = {w0.x, w0.y, w0.z, w0.w, w1.x, w1.y, w1.z, w1.w};
    #pragma unroll
    for (int i = 0; i < 4; ++i)
      #pragma unroll
      for (int j = 0; j < 8; ++j) acc[i][j] += av[i]*wv[j];
  }

  #pragma unroll
  for (int i = 0; i < 4; ++i){
    int n = n0 + n4*4 + i;
    if (n >= NN) continue;
    #pragma unroll
    for (int j = 0; j < 8; ++j){
      int col = j0 + jj*8 + j;
      float v = acc[i][j];
      if (col < 375){
        out1b[(size_t)n*ROWB + col] = f2bf(v);
      } else if (col >= 384 && col < 759){
        baseb[(size_t)n*376 + (col - 384)] = v + preb[l*375 + (col - 384)];
      } else if (col >= 768 && col < 843){
        z[(size_t)n*75 + (col - 768)] = v;
      }
    }
  }
}

// ---- gather-aggregate: 1 wave / node. lanes 0..46 own 8 feats each (uint4).
// writes agg bf16 [n][4 stats][376]  (mean|mn|mx|sd), base folded in.
__device__ __forceinline__ uint4 pack8(const float* v){
  uint4 r;
  r.x = (unsigned)f2bf(v[0]) | ((unsigned)f2bf(v[1]) << 16);
  r.y = (unsigned)f2bf(v[2]) | ((unsigned)f2bf(v[3]) << 16);
  r.z = (unsigned)f2bf(v[4]) | ((unsigned)f2bf(v[5]) << 16);
  r.w = (unsigned)f2bf(v[6]) | ((unsigned)f2bf(v[7]) << 16);
  return r;
}

__global__ __launch_bounds__(256) void k_gather(
    const unsigned short* __restrict__ out1b, const float* __restrict__ baseb,
    const int* __restrict__ off, const int* __restrict__ csr,
    unsigned short* __restrict__ agg){
  int gid = blockIdx.x*256 + threadIdx.x;
  int n = gid >> 6;
  int lane = gid & 63;
  if (n >= NN || lane >= 47) return;
  int fo = lane*8;
  float s[8], ss[8], mn[8], mx[8];
  #pragma unroll
  for (int j = 0; j < 8; ++j){ s[j]=0.f; ss[j]=0.f; mn[j]=3.4e38f; mx[j]=-3.4e38f; }
  int e0 = off[n], e1 = off[n+1], deg = e1 - e0;

#define STT(v,J){ float _v=(v); s[J]+=_v; ss[J]+=_v*_v; mn[J]=fminf(mn[J],_v); mx[J]=fmaxf(mx[J],_v); }
#define PR(X){ STT(blo((X).x),0) STT(bhi((X).x),1) STT(blo((X).y),2) STT(bhi((X).y),3) \
               STT(blo((X).z),4) STT(bhi((X).z),5) STT(blo((X).w),6) STT(bhi((X).w),7) }
  int k = e0;
  for (; k + 4 <= e1; k += 4){
    uint4 a  = *(const uint4*)(out1b + (size_t)csr[k]  *ROWB + fo);
    uint4 b  = *(const uint4*)(out1b + (size_t)csr[k+1]*ROWB + fo);
    uint4 c  = *(const uint4*)(out1b + (size_t)csr[k+2]*ROWB + fo);
    uint4 d2 = *(const uint4*)(out1b + (size_t)csr[k+3]*ROWB + fo);
    PR(a) PR(b) PR(c) PR(d2)
  }
  for (; k < e1; ++k){
    uint4 a = *(const uint4*)(out1b + (size_t)csr[k]*ROWB + fo);
    PR(a)
  }
#undef PR
#undef STT

  float mean[8], sd[8];
  if (deg > 0){
    float rd = 1.f/(float)deg;
    float4 b0 = *(const float4*)(baseb + (size_t)n*376 + fo);
    float4 b1 = *(const float4*)(baseb + (size_t)n*376 + fo + 4);
    float bs[8] = {b0.x,b0.y,b0.z,b0.w,b1.x,b1.y,b1.z,b1.w};
    #pragma unroll
    for (int j = 0; j < 8; ++j){
      float mb = s[j]*rd;
      float var = ss[j]*rd - mb*mb;
      mean[j] = bs[j] + mb;
      sd[j]   = sqrtf(fmaxf(var, 0.f) + 1e-5f);
      mn[j]   = bs[j] + mn[j];
      mx[j]   = bs[j] + mx[j];
    }
  } else {
    #pragma unroll
    for (int j = 0; j < 8; ++j){ mean[j]=0.f; mn[j]=0.f; mx[j]=0.f; sd[j]=sqrtf(1e-5f); }
  }
  unsigned short* ap = agg + (size_t)n*1504 + fo;
  *(uint4*)(ap)        = pack8(mean);
  *(uint4*)(ap + 376)  = pack8(mn);
  *(uint4*)(ap + 752)  = pack8(mx);
  *(uint4*)(ap + 1128) = pack8(sd);
}

// ---- post: per-tower GEMM (K=300,N=48 from agg) + scalers + lin + BN-sums
// block = 16 nodes, 256 threads (gq=node 0..15, fo=group 0..15).
__global__ __launch_bounds__(256) void k_post(
    const unsigned short* __restrict__ agg, const float* __restrict__ z,
    const int* __restrict__ off,
    const float* __restrict__ W45, const float* __restrict__ postb,
    const float* __restrict__ linW, const float* __restrict__ linb,
    float* __restrict__ out2, float* __restrict__ bnS1, int l){
  __shared__ float As[16][308];     // 308%32=20 -> 2-way banks (free); reused as red
  __shared__ float part[48][17];
  __shared__ float zmid[16][78];
  __shared__ float dln[16];
  int tid = threadIdx.x;
  int n0 = blockIdx.x*16;
  if (tid < 16){
    int dd = off[n0+tid+1] - off[n0+tid];
    dln[tid] = (float)(dd > 0 ? dd : 1);
  }
  int gq = tid & 15, fo = tid >> 4;
  for (int t = 0; t < NT; ++t){
    for (int idx = tid; idx < 4800; idx += 256){
      int nl = idx/300, c = idx - nl*300;
      int st = c/75, u = c - st*75;
      unsigned short raw = agg[(size_t)(n0+nl)*1504 + st*376 + t*75 + u];
      As[nl][c] = __uint_as_float(((unsigned)raw) << 16);
    }
    __syncthreads();
    float a0 = 0.f, a1 = 0.f, a2 = 0.f;
    const float4* wp = (const float4*)(W45 + (size_t)((l*NT + t)*300)*64);
    for (int cb = 0; cb < 300; cb += 4){
      float4 av = *(const float4*)&As[gq][cb];
      float4 w0 = wp[(cb+0)*16 + fo];
      float4 w1 = wp[(cb+1)*16 + fo];
      float4 w2 = wp[(cb+2)*16 + fo];
      float4 w3 = wp[(cb+3)*16 + fo];
      a0 += av.x*w0.x; a1 += av.x*w0.y; a2 += av.x*w0.z;
      a0 += av.y*w1.x; a1 += av.y*w1.y; a2 += av.y*w1.z;
      a0 += av.z*w2.x; a1 += av.z*w2.y; a2 += av.z*w2.z;
      a0 += av.w*w3.x; a1 += av.w*w3.y; a2 += av.w*w3.z;
    }
    part[fo*3+0][gq] = a0; part[fo*3+1][gq] = a1; part[fo*3+2][gq] = a2;
    __syncthreads();
    if (tid < 240){
      int nl2 = tid/15, f2 = tid - nl2*15;
      float dd = dln[nl2];
      float logd = logf(dd + 1.f);
      float amp = logd*(1.f/LOG17), att = LOG17/logd;
      zmid[nl2][t*15+f2] = z[(size_t)(n0+nl2)*75 + t*15+f2]
        + part[f2][nl2] + amp*part[15+f2][nl2] + att*part[30+f2][nl2]
        + postb[(l*NT+t)*15 + f2];
    }
    // no barrier needed: next stage writes As only; epilogue reads part/zmid.
  }
  __syncthreads();

  // ---------- lin: zmid @ linW + linb, with BN partial sums
  float* red1 = &As[0][0];
  float* red2 = red1 + 75*17;
  if (tid < 240){
    int lnl = tid & 15, oo = tid >> 4;    // oo 0..14
    int o0 = oo*5;
    float lacc[5] = {0.f,0.f,0.f,0.f,0.f};
    const float* lw = linW + (size_t)l*5625;
    for (int c = 0; c < 75; ++c){
      float a = zmid[lnl][c];
      #pragma unroll
      for (int k2 = 0; k2 < 5; ++k2) lacc[k2] += a * lw[c*75 + o0 + k2];
    }
    #pragma unroll
    for (int k2 = 0; k2 < 5; ++k2){
      float v = lacc[k2] + linb[l*75 + o0 + k2];
      out2[(size_t)(n0+lnl)*75 + o0 + k2] = v;
      red1[(o0+k2)*17 + lnl] = v;
      red2[(o0+k2)*17 + lnl] = v*v;
    }
  }
  __syncthreads();
  if (tid < 75){
    float b1 = 0.f, b2 = 0.f;
    #pragma unroll
    for (int jj = 0; jj < 16; ++jj){ b1 += red1[tid*17+jj]; b2 += red2[tid*17+jj]; }
    atomicAdd(&bnS1[tid], b1);
    atomicAdd(&bnS1[80+tid], b2);
  }
}

// -------------------------------- final BN+ReLU fused with global_add_pool
__global__ __launch_bounds__(256) void k_bnpool(const float* __restrict__ out2,
    const float* __restrict__ bnSp, const float* __restrict__ sc,
    const float* __restrict__ bb, const int* __restrict__ batch,
    float* __restrict__ pooled){
  int i = blockIdx.x*256 + threadIdx.x;
  if (i >= NN*75) return;
  int n = i / 75, f = i - n*75;
  float mu = bnSp[f] * (1.f/NN);
  float var = bnSp[80 + f] * (1.f/NN) - mu*mu;
  float v = fmaxf((out2[i] - mu) / sqrtf(var + 1e-5f) * sc[f] + bb[f], 0.f);
  atomicAdd(&pooled[batch[n]*75 + f], v);
}

__global__ __launch_bounds__(256) void k_head(const float* __restrict__ pooled,
    const float* __restrict__ W1, const float* __restrict__ b1,
    const float* __restrict__ W2, const float* __restrict__ b2,
    const float* __restrict__ W3, const float* __restrict__ b3,
    float* __restrict__ out){
  __shared__ float pl[64*75];
  __shared__ float w1[75*50];
  __shared__ float z1[64*50];
  __shared__ float w2[50*25];
  __shared__ float z2[64*25];
  __shared__ float w3[25];
  __shared__ float bb1[50], bb2[25];
  int tid = threadIdx.x;
  for (int i = tid; i < 64*75; i += 256) pl[i] = pooled[i];
  for (int i = tid; i < 75*50; i += 256) w1[i] = W1[i];
  for (int i = tid; i < 50*25; i += 256) w2[i] = W2[i];
  if (tid < 25) w3[tid] = W3[tid];
  if (tid < 50) bb1[tid] = b1[tid];
  if (tid < 25) bb2[tid] = b2[tid];
  __syncthreads();
  for (int o = tid; o < 64*50; o += 256){
    int g = o / 50, j = o - g*50;
    float acc = bb1[j];
    for (int c = 0; c < 75; ++c) acc += pl[g*75 + c] * w1[c*50 + j];
    z1[o] = fmaxf(acc, 0.f);
  }
  __syncthreads();
  for (int o = tid; o < 64*25; o += 256){
    int g = o / 25, j = o - g*25;
    float acc = bb2[j];
    for (int c = 0; c < 50; ++c) acc += z1[g*50 + c] * w2[c*25 + j];
    z2[o] = fmaxf(acc, 0.f);
  }
  __syncthreads();
  if (tid < 64){
    float acc = b3[0];
    for (int c = 0; c < 25; ++c) acc += z2[tid*25 + c] * w3[c];
    out[tid] = acc;
  }
}

// ---------------------------------------------------------------- launcher
extern "C" void kernel_launch(void* const* d_in, const int* in_sizes, int n_in,
                              void* d_out, int out_size, void* d_ws, size_t ws_size,
                              hipStream_t stream){
  const float* x     = (const float*)d_in[0];
  const int*   ei    = (const int*)  d_in[1];
  const int*   batch = (const int*)  d_in[2];
  const float* plW   = (const float*)d_in[3];
  const float* plb   = (const float*)d_in[4];
  const float* preW  = (const float*)d_in[5];
  const float* preb  = (const float*)d_in[6];
  const float* postW = (const float*)d_in[7];
  const float* postb = (const float*)d_in[8];
  const float* linW  = (const float*)d_in[9];
  const float* linb  = (const float*)d_in[10];
  const float* bns   = (const float*)d_in[11];
  const float* bnb   = (const float*)d_in[12];
  const float* W1    = (const float*)d_in[13];
  const float* b1    = (const float*)d_in[14];
  const float* W2    = (const float*)d_in[15];
  const float* b2    = (const float*)d_in[16];
  const float* W3    = (const float*)d_in[17];
  const float* b3    = (const float*)d_in[18];
  float* out = (float*)d_out;

  // workspace layout (~65.2 MB; R0 demonstrated >= 66.0 MB available)
  float* h0    = (float*)d_ws;                     // 750000
  float* out2v = h0 + 750000;                      // 750000
  float* zv    = out2v + 750000;                   // 750000
  float* baseb = zv + 750000;                      // NN*376 f32
  float* Wcat  = baseb + (size_t)NN*376;           // 4*75*896
  float* W45   = Wcat + NL*75*WCN;                 // 4*5*300*64
  float* pooled= W45 + NL*NT*300*64;               // 4800
  float* bnS   = pooled + 4800;                    // 4*160
  unsigned short* out1b = (unsigned short*)(bnS + NL*160);  // NN*384
  unsigned short* aggb  = out1b + (size_t)NN*ROWB;          // NN*1504
  int* cnt = (int*)(aggb + (size_t)NN*1504);
  int* off = cnt + NN;
  int* cur = off + NN + 1;
  int* csr = cur + NN;

  hipMemsetAsync(cnt, 0, NN*sizeof(int), stream);
  hipMemsetAsync(bnS, 0, NL*160*sizeof(float), stream);
  hipMemsetAsync(pooled, 0, 4800*sizeof(float), stream);
  hipMemsetAsync(out1b, 0, (size_t)NN*ROWB*sizeof(unsigned short), stream);
  k_init_h<<<(NN*NF + 255)/256, 256, 0, stream>>>(x, plW, plb, h0);
  k_count<<<(NE + 255)/256, 256, 0, stream>>>(ei, cnt);
  k_scan<<<1, 1024, 0, stream>>>(cnt, off, cur);
  k_scatter<<<(NE + 255)/256, 256, 0, stream>>>(ei, cur, csr);
  k_buildWcat<<<(NL*75*WCN + 255)/256, 256, 0, stream>>>(preW, postW, Wcat);
  k_buildW45<<<(NL*NT*300*64 + 255)/256, 256, 0, stream>>>(postW, W45);

  for (int l = 0; l < NL; ++l){
    const float* src = (l == 0) ? h0 : out2v;
    const float* bnSp = bnS + (l > 0 ? (l-1)*160 : 0);
    const float* sc = bns + (l > 0 ? (l-1)*75 : 0);
    const float* bb = bnb + (l > 0 ? (l-1)*75 : 0);
    k_gemm1<<<157*7, 256, 0, stream>>>(src, Wcat, preb, bnSp, sc, bb, (l > 0),
                                       out1b, baseb, zv, l);
    k_gather<<<(NN*64)/256, 256, 0, stream>>>(out1b, baseb, off, csr, aggb);
    k_post<<<NN/16, 256, 0, stream>>>(aggb, zv, off, W45, postb,
                                      linW, linb, out2v, bnS + l*160, l);
  }

  k_bnpool<<<(NN*NF + 255)/256, 256, 0, stream>>>(out2v, bnS + 3*160,
                                                  bns + 3*75, bnb + 3*75, batch, pooled);
  k_head<<<1, 256, 0, stream>>>(pooled, W1, b1, W2, b2, W3, b3, out);
}

// Round 8
// 1024.544 us; speedup vs baseline: 1.2455x; 1.0490x over previous
//
#include <hip/hip_runtime.h>

#define NN 10000
#define NE 160000
#define NG 64
#define NT 5
#define NF 75
#define NL 4
#define LOG17 2.8332133f  /* log(17.0) */
#define ROWB 384          /* bf16 B row stride (375 used, pads zeroed once) */
#define WCN 896           /* Wcat cols: B 0..374 | base 384..758 | y0 768..842 | pad */

__device__ __forceinline__ unsigned short f2bf(float x){
  unsigned u = __float_as_uint(x);
  unsigned r = (u + 0x7FFFu + ((u >> 16) & 1u)) >> 16;
  return (unsigned short)r;
}
__device__ __forceinline__ float blo(unsigned u){ return __uint_as_float(u << 16); }
__device__ __forceinline__ float bhi(unsigned u){ return __uint_as_float(u & 0xFFFF0000u); }

// ---------------------------------------------------------------- setup
__global__ __launch_bounds__(256) void k_init_h(const float* __restrict__ x,
    const float* __restrict__ W, const float* __restrict__ b, float* __restrict__ h){
  int i = blockIdx.x*256 + threadIdx.x;
  if (i >= NN*NF) return;
  int n = i / NF, f = i - n*NF;
  h[i] = x[2*n]*W[f] + x[2*n+1]*W[NF+f] + b[f];
}

__global__ __launch_bounds__(256) void k_count(const int* __restrict__ ei, int* __restrict__ cnt){
  int e = blockIdx.x*256 + threadIdx.x;
  if (e < NE) atomicAdd(&cnt[ei[NE + e]], 1);   // row 1 = dst
}

__global__ __launch_bounds__(1024) void k_scan(const int* __restrict__ cnt,
    int* __restrict__ off, int* __restrict__ cur){
  __shared__ int buf[1024];
  __shared__ int carry;
  int tid = threadIdx.x;
  if (tid == 0) carry = 0;
  __syncthreads();
  for (int base = 0; base < NN; base += 1024){
    int i = base + tid;
    int v = (i < NN) ? cnt[i] : 0;
    buf[tid] = v;
    __syncthreads();
    for (int d = 1; d < 1024; d <<= 1){
      int t = (tid >= d) ? buf[tid - d] : 0;
      __syncthreads();
      buf[tid] += t;
      __syncthreads();
    }
    int c = carry;
    if (i < NN){ int ex = c + buf[tid] - v; off[i] = ex; cur[i] = ex; }
    int tot = buf[1023];
    __syncthreads();
    if (tid == 0) carry = c + tot;
    __syncthreads();
  }
  if (tid == 0) off[NN] = NE;
}

__global__ __launch_bounds__(256) void k_scatter(const int* __restrict__ ei,
    int* __restrict__ cur, int* __restrict__ csr){
  int e = blockIdx.x*256 + threadIdx.x;
  if (e < NE){
    int d = ei[NE + e];
    int p = atomicAdd(&cur[d], 1);
    csr[p] = ei[e];   // src node
  }
}

// Wcat[l][75][896]
__global__ __launch_bounds__(256) void k_buildWcat(const float* __restrict__ preW,
    const float* __restrict__ postW, float* __restrict__ Wcat){
  int idx = blockIdx.x*256 + threadIdx.x;
  if (idx >= NL*75*WCN) return;
  int l = idx / (75*WCN);
  int rem = idx - l*75*WCN;
  int c = rem / WCN, j = rem - c*WCN;
  float v = 0.f;
  if (j < 375){
    int t = j/75, f = j - t*75;
    v = preW[(size_t)((l*NT + t)*150 + 75 + c)*75 + f];
  } else if (j >= 384 && j < 759){
    int jj = j - 384; int t = jj/75, f = jj - t*75;
    v = preW[(size_t)((l*NT + t)*150 + c)*75 + f];
  } else if (j >= 768 && j < 843){
    int jj = j - 768; int t = jj/15, f2 = jj - t*15;
    v = postW[(size_t)((l*NT + t)*975 + c)*15 + f2];
  }
  Wcat[idx] = v;
}

// W45[l][t][300][64] f32: col = 4*(f48/3) + f48%3 ; col%4==3 -> 0
__global__ __launch_bounds__(256) void k_buildW45(const float* __restrict__ postW,
    float* __restrict__ W45){
  int idx = blockIdx.x*256 + threadIdx.x;
  if (idx >= NL*NT*300*64) return;
  int l = idx / (NT*300*64);
  int rem = idx - l*NT*300*64;
  int t = rem / (300*64);
  int rem2 = rem - t*300*64;
  int c = rem2 / 64, col = rem2 - c*64;
  int g3 = col >> 2, e = col & 3;
  float v = 0.f;
  if (e < 3){
    int f48 = g3*3 + e;             // [0,48)
    int g = f48/15, f2 = f48 - g*15;
    if (g < 3)
      v = postW[(size_t)((l*NT + t)*975 + 75 + g*300 + c)*15 + f2];
  }
  W45[idx] = v;
}

// ------ GEMM1: [B(bf16) | base(+preb) | y0] = src(BN?) @ Wcat.  M=10000,K=75
__global__ __launch_bounds__(256) void k_gemm1(const float* __restrict__ src,
    const float* __restrict__ Wcat, const float* __restrict__ preb,
    const float* __restrict__ bnSp, const float* __restrict__ sc,
    const float* __restrict__ bb, int use_bn,
    unsigned short* __restrict__ out1b, float* __restrict__ baseb,
    float* __restrict__ z, int l){
  __shared__ float As[75][68];
  __shared__ float Ws[75][128];
  int tid = threadIdx.x;
  int bid = blockIdx.x;
  int nt = bid / 7, jt = bid - nt*7;
  int n0 = nt*64, j0 = jt*128;

  for (int idx = tid; idx < 64*75; idx += 256){
    int i = idx/75, c = idx - i*75;
    float v = (n0 + i < NN) ? src[(size_t)n0*75 + idx] : 0.f;
    if (use_bn){
      float mu = bnSp[c] * (1.f/NN);
      float var = bnSp[80 + c] * (1.f/NN) - mu*mu;
      v = fmaxf((v - mu) / sqrtf(var + 1e-5f) * sc[c] + bb[c], 0.f);
    }
    As[c][i] = v;
  }
  const float* wg = Wcat + (size_t)l*75*WCN;
  for (int idx = tid; idx < 75*128; idx += 256){
    int c = idx >> 7, j = idx & 127;
    Ws[c][j] = wg[(size_t)c*WCN + j0 + j];
  }
  __syncthreads();

  int jj = tid >> 4, n4 = tid & 15;
  float acc[4][8];
  #pragma unroll
  for (int i = 0; i < 4; ++i)
    #pragma unroll
    for (int j = 0; j < 8; ++j) acc[i][j] = 0.f;

  for (int c = 0; c < 75; ++c){
    float4 a = *reinterpret_cast<const float4*>(&As[c][n4*4]);
    float4 w0 = *reinterpret_cast<const float4*>(&Ws[c][jj*8]);
    float4 w1 = *reinterpret_cast<const float4*>(&Ws[c][jj*8 + 4]);
    float av[4] = {a.x, a.y, a.z, a.w};
    float wv[8] = {w0.x, w0.y, w0.z, w0.w, w1.x, w1.y, w1.z, w1.w};
    #pragma unroll
    for (int i = 0; i < 4; ++i)
      #pragma unroll
      for (int j = 0; j < 8; ++j) acc[i][j] += av[i]*wv[j];
  }

  #pragma unroll
  for (int i = 0; i < 4; ++i){
    int n = n0 + n4*4 + i;
    if (n >= NN) continue;
    #pragma unroll
    for (int j = 0; j < 8; ++j){
      int col = j0 + jj*8 + j;
      float v = acc[i][j];
      if (col < 375){
        out1b[(size_t)n*ROWB + col] = f2bf(v);
      } else if (col >= 384 && col < 759){
        baseb[(size_t)n*376 + (col - 384)] = v + preb[l*375 + (col - 384)];
      } else if (col >= 768 && col < 843){
        z[(size_t)n*75 + (col - 768)] = v;
      }
    }
  }
}

// ---- gather-aggregate: 1 wave / node. lanes 0..46 own 8 feats each (uint4).
// writes agg bf16 [n][4 stats][376]  (mean|mn|mx|sd), base folded in.
__device__ __forceinline__ uint4 pack8(const float* v){
  uint4 r;
  r.x = (unsigned)f2bf(v[0]) | ((unsigned)f2bf(v[1]) << 16);
  r.y = (unsigned)f2bf(v[2]) | ((unsigned)f2bf(v[3]) << 16);
  r.z = (unsigned)f2bf(v[4]) | ((unsigned)f2bf(v[5]) << 16);
  r.w = (unsigned)f2bf(v[6]) | ((unsigned)f2bf(v[7]) << 16);
  return r;
}

__global__ __launch_bounds__(256) void k_gather(
    const unsigned short* __restrict__ out1b, const float* __restrict__ baseb,
    const int* __restrict__ off, const int* __restrict__ csr,
    unsigned short* __restrict__ agg){
  int gid = blockIdx.x*256 + threadIdx.x;
  int n = gid >> 6;
  int lane = gid & 63;
  if (n >= NN || lane >= 47) return;
  int fo = lane*8;
  float s[8], ss[8], mn[8], mx[8];
  #pragma unroll
  for (int j = 0; j < 8; ++j){ s[j]=0.f; ss[j]=0.f; mn[j]=3.4e38f; mx[j]=-3.4e38f; }
  int e0 = off[n], e1 = off[n+1], deg = e1 - e0;

#define STT(v,J){ float _v=(v); s[J]+=_v; ss[J]+=_v*_v; mn[J]=fminf(mn[J],_v); mx[J]=fmaxf(mx[J],_v); }
#define PR(X){ STT(blo((X).x),0) STT(bhi((X).x),1) STT(blo((X).y),2) STT(bhi((X).y),3) \
               STT(blo((X).z),4) STT(bhi((X).z),5) STT(blo((X).w),6) STT(bhi((X).w),7) }
  int k = e0;
  for (; k + 4 <= e1; k += 4){
    uint4 a  = *(const uint4*)(out1b + (size_t)csr[k]  *ROWB + fo);
    uint4 b  = *(const uint4*)(out1b + (size_t)csr[k+1]*ROWB + fo);
    uint4 c  = *(const uint4*)(out1b + (size_t)csr[k+2]*ROWB + fo);
    uint4 d2 = *(const uint4*)(out1b + (size_t)csr[k+3]*ROWB + fo);
    PR(a) PR(b) PR(c) PR(d2)
  }
  for (; k < e1; ++k){
    uint4 a = *(const uint4*)(out1b + (size_t)csr[k]*ROWB + fo);
    PR(a)
  }
#undef PR
#undef STT

  float mean[8], sd[8];
  if (deg > 0){
    float rd = 1.f/(float)deg;
    float4 b0 = *(const float4*)(baseb + (size_t)n*376 + fo);
    float4 b1 = *(const float4*)(baseb + (size_t)n*376 + fo + 4);
    float bs[8] = {b0.x,b0.y,b0.z,b0.w,b1.x,b1.y,b1.z,b1.w};
    #pragma unroll
    for (int j = 0; j < 8; ++j){
      float mb = s[j]*rd;
      float var = ss[j]*rd - mb*mb;
      mean[j] = bs[j] + mb;
      sd[j]   = sqrtf(fmaxf(var, 0.f) + 1e-5f);
      mn[j]   = bs[j] + mn[j];
      mx[j]   = bs[j] + mx[j];
    }
  } else {
    #pragma unroll
    for (int j = 0; j < 8; ++j){ mean[j]=0.f; mn[j]=0.f; mx[j]=0.f; sd[j]=sqrtf(1e-5f); }
  }
  unsigned short* ap = agg + (size_t)n*1504 + fo;
  *(uint4*)(ap)        = pack8(mean);
  *(uint4*)(ap + 376)  = pack8(mn);
  *(uint4*)(ap + 752)  = pack8(mx);
  *(uint4*)(ap + 1128) = pack8(sd);
}

// ---- post: one (16-node tile, tower) per block. GEMM K=300,N=48 + scalers,
// accumulates into z in place (tower-disjoint columns). grid = 5*(NN/16).
__global__ __launch_bounds__(256) void k_post(
    const unsigned short* __restrict__ agg, float* __restrict__ z,
    const int* __restrict__ off,
    const float* __restrict__ W45, const float* __restrict__ postb, int l){
  __shared__ float As[16][308];     // 308%32=20 -> benign banking
  __shared__ float part[48][17];
  __shared__ float dln[16];
  int tid = threadIdx.x;
  int bid = blockIdx.x;
  int t = bid / (NN/16);            // tower-major: consecutive bids share W45 slice
  int nt = bid - t*(NN/16);
  int n0 = nt*16;
  if (tid < 16){
    int dd = off[n0+tid+1] - off[n0+tid];
    dln[tid] = (float)(dd > 0 ? dd : 1);
  }
  for (int idx = tid; idx < 4800; idx += 256){
    int nl = idx/300, c = idx - nl*300;
    int st = c/75, u = c - st*75;
    unsigned short raw = agg[(size_t)(n0+nl)*1504 + st*376 + t*75 + u];
    As[nl][c] = __uint_as_float(((unsigned)raw) << 16);
  }
  __syncthreads();
  int gq = tid & 15, fo = tid >> 4;
  float a0 = 0.f, a1 = 0.f, a2 = 0.f;
  const float4* wp = (const float4*)(W45 + (size_t)((l*NT + t)*300)*64);
  for (int cb = 0; cb < 300; cb += 4){
    float4 av = *(const float4*)&As[gq][cb];
    float4 w0 = wp[(cb+0)*16 + fo];
    float4 w1 = wp[(cb+1)*16 + fo];
    float4 w2 = wp[(cb+2)*16 + fo];
    float4 w3 = wp[(cb+3)*16 + fo];
    a0 += av.x*w0.x; a1 += av.x*w0.y; a2 += av.x*w0.z;
    a0 += av.y*w1.x; a1 += av.y*w1.y; a2 += av.y*w1.z;
    a0 += av.z*w2.x; a1 += av.z*w2.y; a2 += av.z*w2.z;
    a0 += av.w*w3.x; a1 += av.w*w3.y; a2 += av.w*w3.z;
  }
  part[fo*3+0][gq] = a0; part[fo*3+1][gq] = a1; part[fo*3+2][gq] = a2;
  __syncthreads();
  if (tid < 240){
    int nl2 = tid/15, f2 = tid - nl2*15;
    float dd = dln[nl2];
    float logd = logf(dd + 1.f);
    float amp = logd*(1.f/LOG17), att = LOG17/logd;
    size_t zi = (size_t)(n0+nl2)*75 + t*15 + f2;
    z[zi] = z[zi] + part[f2][nl2] + amp*part[15+f2][nl2] + att*part[30+f2][nl2]
          + postb[(l*NT+t)*15 + f2];
  }
}

// ------ mixing lin: out2 = z @ linW + linb; fused BN partial sums (atomics)
__global__ __launch_bounds__(256) void k_lin(const float* __restrict__ z,
    const float* __restrict__ linW, const float* __restrict__ linb,
    float* __restrict__ out2, float* __restrict__ bnS1, int l){
  __shared__ float zs[75][68];
  __shared__ float lw[75][80];
  int tid = threadIdx.x;
  int n0 = blockIdx.x*64;
  for (int idx = tid; idx < 64*75; idx += 256){
    int i = idx/75, c = idx - i*75;
    zs[c][i] = (n0 + i < NN) ? z[(size_t)n0*75 + idx] : 0.f;
  }
  for (int idx = tid; idx < 75*80; idx += 256){
    int c = idx/80, o = idx - c*80;
    lw[c][o] = (o < 75) ? linW[(size_t)l*5625 + c*75 + o] : 0.f;
  }
  __syncthreads();
  int og = tid >> 4, n4 = tid & 15;
  int o0 = og*5;
  float acc[4][5];
  #pragma unroll
  for (int i = 0; i < 4; ++i)
    #pragma unroll
    for (int k = 0; k < 5; ++k) acc[i][k] = 0.f;
  for (int c = 0; c < 75; ++c){
    float4 a = *reinterpret_cast<const float4*>(&zs[c][n4*4]);
    float av[4] = {a.x, a.y, a.z, a.w};
    float wv[5];
    #pragma unroll
    for (int k = 0; k < 5; ++k) wv[k] = lw[c][o0 + k];
    #pragma unroll
    for (int i = 0; i < 4; ++i)
      #pragma unroll
      for (int k = 0; k < 5; ++k) acc[i][k] += av[i]*wv[k];
  }
  float s1p[5], s2p[5];
  #pragma unroll
  for (int k = 0; k < 5; ++k){ s1p[k] = 0.f; s2p[k] = 0.f; }
  #pragma unroll
  for (int i = 0; i < 4; ++i){
    int n = n0 + n4*4 + i;
    if (n >= NN) continue;
    #pragma unroll
    for (int k = 0; k < 5; ++k){
      int o = o0 + k;
      if (o < 75){
        float v = acc[i][k] + linb[l*75 + o];
        out2[(size_t)n*75 + o] = v;
        s1p[k] += v; s2p[k] += v*v;
      }
    }
  }
  __syncthreads();
  float* red = &zs[0][0];          // [75][16] s1, then [75][16] s2
  #pragma unroll
  for (int k = 0; k < 5; ++k){
    int o = o0 + k;
    if (o < 75){ red[o*16 + n4] = s1p[k]; red[1200 + o*16 + n4] = s2p[k]; }
  }
  __syncthreads();
  if (tid < 75){
    float a1 = 0.f, a2 = 0.f;
    #pragma unroll
    for (int j = 0; j < 16; ++j){ a1 += red[tid*16 + j]; a2 += red[1200 + tid*16 + j]; }
    atomicAdd(&bnS1[tid], a1);
    atomicAdd(&bnS1[80 + tid], a2);
  }
}

// -------------------------------- final BN+ReLU fused with global_add_pool
__global__ __launch_bounds__(256) void k_bnpool(const float* __restrict__ out2,
    const float* __restrict__ bnSp, const float* __restrict__ sc,
    const float* __restrict__ bb, const int* __restrict__ batch,
    float* __restrict__ pooled){
  int i = blockIdx.x*256 + threadIdx.x;
  if (i >= NN*75) return;
  int n = i / 75, f = i - n*75;
  float mu = bnSp[f] * (1.f/NN);
  float var = bnSp[80 + f] * (1.f/NN) - mu*mu;
  float v = fmaxf((out2[i] - mu) / sqrtf(var + 1e-5f) * sc[f] + bb[f], 0.f);
  atomicAdd(&pooled[batch[n]*75 + f], v);
}

__global__ __launch_bounds__(256) void k_head(const float* __restrict__ pooled,
    const float* __restrict__ W1, const float* __restrict__ b1,
    const float* __restrict__ W2, const float* __restrict__ b2,
    const float* __restrict__ W3, const float* __restrict__ b3,
    float* __restrict__ out){
  __shared__ float pl[64*75];
  __shared__ float w1[75*50];
  __shared__ float z1[64*50];
  __shared__ float w2[50*25];
  __shared__ float z2[64*25];
  __shared__ float w3[25];
  __shared__ float bb1[50], bb2[25];
  int tid = threadIdx.x;
  for (int i = tid; i < 64*75; i += 256) pl[i] = pooled[i];
  for (int i = tid; i < 75*50; i += 256) w1[i] = W1[i];
  for (int i = tid; i < 50*25; i += 256) w2[i] = W2[i];
  if (tid < 25) w3[tid] = W3[tid];
  if (tid < 50) bb1[tid] = b1[tid];
  if (tid < 25) bb2[tid] = b2[tid];
  __syncthreads();
  for (int o = tid; o < 64*50; o += 256){
    int g = o / 50, j = o - g*50;
    float acc = bb1[j];
    for (int c = 0; c < 75; ++c) acc += pl[g*75 + c] * w1[c*50 + j];
    z1[o] = fmaxf(acc, 0.f);
  }
  __syncthreads();
  for (int o = tid; o < 64*25; o += 256){
    int g = o / 25, j = o - g*25;
    float acc = bb2[j];
    for (int c = 0; c < 50; ++c) acc += z1[g*50 + c] * w2[c*25 + j];
    z2[o] = fmaxf(acc, 0.f);
  }
  __syncthreads();
  if (tid < 64){
    float acc = b3[0];
    for (int c = 0; c < 25; ++c) acc += z2[tid*25 + c] * w3[c];
    out[tid] = acc;
  }
}

// ---------------------------------------------------------------- launcher
extern "C" void kernel_launch(void* const* d_in, const int* in_sizes, int n_in,
                              void* d_out, int out_size, void* d_ws, size_t ws_size,
                              hipStream_t stream){
  const float* x     = (const float*)d_in[0];
  const int*   ei    = (const int*)  d_in[1];
  const int*   batch = (const int*)  d_in[2];
  const float* plW   = (const float*)d_in[3];
  const float* plb   = (const float*)d_in[4];
  const float* preW  = (const float*)d_in[5];
  const float* preb  = (const float*)d_in[6];
  const float* postW = (const float*)d_in[7];
  const float* postb = (const float*)d_in[8];
  const float* linW  = (const float*)d_in[9];
  const float* linb  = (const float*)d_in[10];
  const float* bns   = (const float*)d_in[11];
  const float* bnb   = (const float*)d_in[12];
  const float* W1    = (const float*)d_in[13];
  const float* b1    = (const float*)d_in[14];
  const float* W2    = (const float*)d_in[15];
  const float* b2    = (const float*)d_in[16];
  const float* W3    = (const float*)d_in[17];
  const float* b3    = (const float*)d_in[18];
  float* out = (float*)d_out;

  // workspace layout (~65.2 MB)
  float* h0    = (float*)d_ws;                     // 750000
  float* out2v = h0 + 750000;                      // 750000
  float* zv    = out2v + 750000;                   // 750000
  float* baseb = zv + 750000;                      // NN*376 f32
  float* Wcat  = baseb + (size_t)NN*376;           // 4*75*896
  float* W45   = Wcat + NL*75*WCN;                 // 4*5*300*64
  float* pooled= W45 + NL*NT*300*64;               // 4800
  float* bnS   = pooled + 4800;                    // 4*160
  unsigned short* out1b = (unsigned short*)(bnS + NL*160);  // NN*384
  unsigned short* aggb  = out1b + (size_t)NN*ROWB;          // NN*1504
  int* cnt = (int*)(aggb + (size_t)NN*1504);
  int* off = cnt + NN;
  int* cur = off + NN + 1;
  int* csr = cur + NN;

  hipMemsetAsync(cnt, 0, NN*sizeof(int), stream);
  hipMemsetAsync(bnS, 0, NL*160*sizeof(float), stream);
  hipMemsetAsync(pooled, 0, 4800*sizeof(float), stream);
  hipMemsetAsync(out1b, 0, (size_t)NN*ROWB*sizeof(unsigned short), stream);
  k_init_h<<<(NN*NF + 255)/256, 256, 0, stream>>>(x, plW, plb, h0);
  k_count<<<(NE + 255)/256, 256, 0, stream>>>(ei, cnt);
  k_scan<<<1, 1024, 0, stream>>>(cnt, off, cur);
  k_scatter<<<(NE + 255)/256, 256, 0, stream>>>(ei, cur, csr);
  k_buildWcat<<<(NL*75*WCN + 255)/256, 256, 0, stream>>>(preW, postW, Wcat);
  k_buildW45<<<(NL*NT*300*64 + 255)/256, 256, 0, stream>>>(postW, W45);

  for (int l = 0; l < NL; ++l){
    const float* src = (l == 0) ? h0 : out2v;
    const float* bnSp = bnS + (l > 0 ? (l-1)*160 : 0);
    const float* sc = bns + (l > 0 ? (l-1)*75 : 0);
    const float* bb = bnb + (l > 0 ? (l-1)*75 : 0);
    k_gemm1<<<157*7, 256, 0, stream>>>(src, Wcat, preb, bnSp, sc, bb, (l > 0),
                                       out1b, baseb, zv, l);
    k_gather<<<(NN*64)/256, 256, 0, stream>>>(out1b, baseb, off, csr, aggb);
    k_post<<<NT*(NN/16), 256, 0, stream>>>(aggb, zv, off, W45, postb, l);
    k_lin<<<157, 256, 0, stream>>>(zv, linW, linb, out2v, bnS + l*160, l);
  }

  k_bnpool<<<(NN*NF + 255)/256, 256, 0, stream>>>(out2v, bnS + 3*160,
                                                  bns + 3*75, bnb + 3*75, batch, pooled);
  k_head<<<1, 256, 0, stream>>>(pooled, W1, b1, W2, b2, W3, b3, out);
}

// Round 9
// 795.844 us; speedup vs baseline: 1.6034x; 1.2874x over previous
//
#include <hip/hip_runtime.h>

#define NN 10000
#define NE 160000
#define NG 64
#define NT 5
#define NF 75
#define NL 4
#define LOG17 2.8332133f  /* log(17.0) */
#define ROWB 384          /* bf16 B row stride (375 used, pads zeroed once) */
#define WCN 896           /* Wcat cols: B 0..374 | base 384..758 | y0 768..842 | pad */

__device__ __forceinline__ unsigned short f2bf(float x){
  unsigned u = __float_as_uint(x);
  unsigned r = (u + 0x7FFFu + ((u >> 16) & 1u)) >> 16;
  return (unsigned short)r;
}
__device__ __forceinline__ float blo(unsigned u){ return __uint_as_float(u << 16); }
__device__ __forceinline__ float bhi(unsigned u){ return __uint_as_float(u & 0xFFFF0000u); }

// ---------------------------------------------------------------- setup
__global__ __launch_bounds__(256) void k_init_h(const float* __restrict__ x,
    const float* __restrict__ W, const float* __restrict__ b, float* __restrict__ h){
  int i = blockIdx.x*256 + threadIdx.x;
  if (i >= NN*NF) return;
  int n = i / NF, f = i - n*NF;
  h[i] = x[2*n]*W[f] + x[2*n+1]*W[NF+f] + b[f];
}

__global__ __launch_bounds__(256) void k_count(const int* __restrict__ ei, int* __restrict__ cnt){
  int e = blockIdx.x*256 + threadIdx.x;
  if (e < NE) atomicAdd(&cnt[ei[NE + e]], 1);   // row 1 = dst
}

__global__ __launch_bounds__(1024) void k_scan(const int* __restrict__ cnt,
    int* __restrict__ off, int* __restrict__ cur){
  __shared__ int buf[1024];
  __shared__ int carry;
  int tid = threadIdx.x;
  if (tid == 0) carry = 0;
  __syncthreads();
  for (int base = 0; base < NN; base += 1024){
    int i = base + tid;
    int v = (i < NN) ? cnt[i] : 0;
    buf[tid] = v;
    __syncthreads();
    for (int d = 1; d < 1024; d <<= 1){
      int t = (tid >= d) ? buf[tid - d] : 0;
      __syncthreads();
      buf[tid] += t;
      __syncthreads();
    }
    int c = carry;
    if (i < NN){ int ex = c + buf[tid] - v; off[i] = ex; cur[i] = ex; }
    int tot = buf[1023];
    __syncthreads();
    if (tid == 0) carry = c + tot;
    __syncthreads();
  }
  if (tid == 0) off[NN] = NE;
}

__global__ __launch_bounds__(256) void k_scatter(const int* __restrict__ ei,
    int* __restrict__ cur, int* __restrict__ csr){
  int e = blockIdx.x*256 + threadIdx.x;
  if (e < NE){
    int d = ei[NE + e];
    int p = atomicAdd(&cur[d], 1);
    csr[p] = ei[e];   // src node
  }
}

// Wcat[l][75][896]
__global__ __launch_bounds__(256) void k_buildWcat(const float* __restrict__ preW,
    const float* __restrict__ postW, float* __restrict__ Wcat){
  int idx = blockIdx.x*256 + threadIdx.x;
  if (idx >= NL*75*WCN) return;
  int l = idx / (75*WCN);
  int rem = idx - l*75*WCN;
  int c = rem / WCN, j = rem - c*WCN;
  float v = 0.f;
  if (j < 375){
    int t = j/75, f = j - t*75;
    v = preW[(size_t)((l*NT + t)*150 + 75 + c)*75 + f];
  } else if (j >= 384 && j < 759){
    int jj = j - 384; int t = jj/75, f = jj - t*75;
    v = preW[(size_t)((l*NT + t)*150 + c)*75 + f];
  } else if (j >= 768 && j < 843){
    int jj = j - 768; int t = jj/15, f2 = jj - t*15;
    v = postW[(size_t)((l*NT + t)*975 + c)*15 + f2];
  }
  Wcat[idx] = v;
}

// W45[l][t][300][64] f32: col = 4*(f48/3) + f48%3 ; col%4==3 -> 0
__global__ __launch_bounds__(256) void k_buildW45(const float* __restrict__ postW,
    float* __restrict__ W45){
  int idx = blockIdx.x*256 + threadIdx.x;
  if (idx >= NL*NT*300*64) return;
  int l = idx / (NT*300*64);
  int rem = idx - l*NT*300*64;
  int t = rem / (300*64);
  int rem2 = rem - t*300*64;
  int c = rem2 / 64, col = rem2 - c*64;
  int g3 = col >> 2, e = col & 3;
  float v = 0.f;
  if (e < 3){
    int f48 = g3*3 + e;             // [0,48)
    int g = f48/15, f2 = f48 - g*15;
    if (g < 3)
      v = postW[(size_t)((l*NT + t)*975 + 75 + g*300 + c)*15 + f2];
  }
  W45[idx] = v;
}

// ------ GEMM1: [B(bf16) | base(+preb) | y0] = src(BN?) @ Wcat.  M=10000,K=75
__global__ __launch_bounds__(256) void k_gemm1(const float* __restrict__ src,
    const float* __restrict__ Wcat, const float* __restrict__ preb,
    const float* __restrict__ bnSp, const float* __restrict__ sc,
    const float* __restrict__ bb, int use_bn,
    unsigned short* __restrict__ out1b, float* __restrict__ baseb,
    float* __restrict__ z, int l){
  __shared__ float As[75][68];
  __shared__ float Ws[75][128];
  int tid = threadIdx.x;
  int bid = blockIdx.x;
  int nt = bid / 7, jt = bid - nt*7;
  int n0 = nt*64, j0 = jt*128;

  for (int idx = tid; idx < 64*75; idx += 256){
    int i = idx/75, c = idx - i*75;
    float v = (n0 + i < NN) ? src[(size_t)n0*75 + idx] : 0.f;
    if (use_bn){
      float mu = bnSp[c] * (1.f/NN);
      float var = bnSp[80 + c] * (1.f/NN) - mu*mu;
      v = fmaxf((v - mu) / sqrtf(var + 1e-5f) * sc[c] + bb[c], 0.f);
    }
    As[c][i] = v;
  }
  const float* wg = Wcat + (size_t)l*75*WCN;
  for (int idx = tid; idx < 75*128; idx += 256){
    int c = idx >> 7, j = idx & 127;
    Ws[c][j] = wg[(size_t)c*WCN + j0 + j];
  }
  __syncthreads();

  int jj = tid >> 4, n4 = tid & 15;
  float acc[4][8];
  #pragma unroll
  for (int i = 0; i < 4; ++i)
    #pragma unroll
    for (int j = 0; j < 8; ++j) acc[i][j] = 0.f;

  for (int c = 0; c < 75; ++c){
    float4 a = *reinterpret_cast<const float4*>(&As[c][n4*4]);
    float4 w0 = *reinterpret_cast<const float4*>(&Ws[c][jj*8]);
    float4 w1 = *reinterpret_cast<const float4*>(&Ws[c][jj*8 + 4]);
    float av[4] = {a.x, a.y, a.z, a.w};
    float wv[8] = {w0.x, w0.y, w0.z, w0.w, w1.x, w1.y, w1.z, w1.w};
    #pragma unroll
    for (int i = 0; i < 4; ++i)
      #pragma unroll
      for (int j = 0; j < 8; ++j) acc[i][j] += av[i]*wv[j];
  }

  #pragma unroll
  for (int i = 0; i < 4; ++i){
    int n = n0 + n4*4 + i;
    if (n >= NN) continue;
    #pragma unroll
    for (int j = 0; j < 8; ++j){
      int col = j0 + jj*8 + j;
      float v = acc[i][j];
      if (col < 375){
        out1b[(size_t)n*ROWB + col] = f2bf(v);
      } else if (col >= 384 && col < 759){
        baseb[(size_t)n*376 + (col - 384)] = v + preb[l*375 + (col - 384)];
      } else if (col >= 768 && col < 843){
        z[(size_t)n*75 + (col - 768)] = v;
      }
    }
  }
}

// ---- gather-aggregate: 1 wave / node. lanes 0..46 own 8 feats each (uint4).
// writes agg bf16 [n][4 stats][376]  (mean|mn|mx|sd), base folded in.
__device__ __forceinline__ uint4 pack8(const float* v){
  uint4 r;
  r.x = (unsigned)f2bf(v[0]) | ((unsigned)f2bf(v[1]) << 16);
  r.y = (unsigned)f2bf(v[2]) | ((unsigned)f2bf(v[3]) << 16);
  r.z = (unsigned)f2bf(v[4]) | ((unsigned)f2bf(v[5]) << 16);
  r.w = (unsigned)f2bf(v[6]) | ((unsigned)f2bf(v[7]) << 16);
  return r;
}

__global__ __launch_bounds__(256) void k_gather(
    const unsigned short* __restrict__ out1b, const float* __restrict__ baseb,
    const int* __restrict__ off, const int* __restrict__ csr,
    unsigned short* __restrict__ agg){
  int gid = blockIdx.x*256 + threadIdx.x;
  int n = gid >> 6;
  int lane = gid & 63;
  if (n >= NN || lane >= 47) return;
  int fo = lane*8;
  float s[8], ss[8], mn[8], mx[8];
  #pragma unroll
  for (int j = 0; j < 8; ++j){ s[j]=0.f; ss[j]=0.f; mn[j]=3.4e38f; mx[j]=-3.4e38f; }
  int e0 = off[n], e1 = off[n+1], deg = e1 - e0;

#define STT(v,J){ float _v=(v); s[J]+=_v; ss[J]+=_v*_v; mn[J]=fminf(mn[J],_v); mx[J]=fmaxf(mx[J],_v); }
#define PR(X){ STT(blo((X).x),0) STT(bhi((X).x),1) STT(blo((X).y),2) STT(bhi((X).y),3) \
               STT(blo((X).z),4) STT(bhi((X).z),5) STT(blo((X).w),6) STT(bhi((X).w),7) }
  int k = e0;
  for (; k + 4 <= e1; k += 4){
    uint4 a  = *(const uint4*)(out1b + (size_t)csr[k]  *ROWB + fo);
    uint4 b  = *(const uint4*)(out1b + (size_t)csr[k+1]*ROWB + fo);
    uint4 c  = *(const uint4*)(out1b + (size_t)csr[k+2]*ROWB + fo);
    uint4 d2 = *(const uint4*)(out1b + (size_t)csr[k+3]*ROWB + fo);
    PR(a) PR(b) PR(c) PR(d2)
  }
  for (; k < e1; ++k){
    uint4 a = *(const uint4*)(out1b + (size_t)csr[k]*ROWB + fo);
    PR(a)
  }
#undef PR
#undef STT

  float mean[8], sd[8];
  if (deg > 0){
    float rd = 1.f/(float)deg;
    float4 b0 = *(const float4*)(baseb + (size_t)n*376 + fo);
    float4 b1 = *(const float4*)(baseb + (size_t)n*376 + fo + 4);
    float bs[8] = {b0.x,b0.y,b0.z,b0.w,b1.x,b1.y,b1.z,b1.w};
    #pragma unroll
    for (int j = 0; j < 8; ++j){
      float mb = s[j]*rd;
      float var = ss[j]*rd - mb*mb;
      mean[j] = bs[j] + mb;
      sd[j]   = sqrtf(fmaxf(var, 0.f) + 1e-5f);
      mn[j]   = bs[j] + mn[j];
      mx[j]   = bs[j] + mx[j];
    }
  } else {
    #pragma unroll
    for (int j = 0; j < 8; ++j){ mean[j]=0.f; mn[j]=0.f; mx[j]=0.f; sd[j]=sqrtf(1e-5f); }
  }
  unsigned short* ap = agg + (size_t)n*1504 + fo;
  *(uint4*)(ap)        = pack8(mean);
  *(uint4*)(ap + 376)  = pack8(mn);
  *(uint4*)(ap + 752)  = pack8(mx);
  *(uint4*)(ap + 1128) = pack8(sd);
}

// ---- post: one (32-node tile, tower) per block. 256 thr = 8 quads x 16 fo x 2 kh.
// Each thread: 4 nodes x 3 cols -> 12 FMA per 16B W45 load. A in LDS as bf16.
__global__ __launch_bounds__(256) void k_post(
    const unsigned short* __restrict__ agg, float* __restrict__ z,
    const int* __restrict__ off,
    const float* __restrict__ W45, const float* __restrict__ postb, int l){
  __shared__ unsigned short As[300][40];   // bf16; row=K idx, col=node (32+8 pad)
  __shared__ float part[2][48][33];
  __shared__ float dln[32];
  int tid = threadIdx.x;
  int bid = blockIdx.x;
  const int NTILE = (NN + 31)/32;          // 313
  int t = bid / NTILE;                     // tower-major: share W45 slice in L2
  int nt = bid - t*NTILE;
  int n0 = nt*32;
  if (tid < 32){
    int n = n0 + tid;
    int dd = (n < NN) ? (off[n+1] - off[n]) : 1;
    dln[tid] = (float)(dd > 0 ? dd : 1);
  }
  // stage: coalesced along c within each node's tower-t slice
  for (int idx = tid; idx < 32*300; idx += 256){
    int nl = idx/300, c = idx - nl*300;
    int n = n0 + nl;
    unsigned short raw = 0;
    if (n < NN){
      int st = c/75, u = c - st*75;
      raw = agg[(size_t)n*1504 + st*376 + t*75 + u];
    }
    As[c][nl] = raw;
  }
  __syncthreads();

  int q  = tid & 7;                 // node quad: nodes q*4 .. q*4+3
  int fo = (tid >> 3) & 15;         // 3 output cols
  int kh = tid >> 7;                // K half
  float acc[4][3];
  #pragma unroll
  for (int i = 0; i < 4; ++i){ acc[i][0]=0.f; acc[i][1]=0.f; acc[i][2]=0.f; }
  const float4* wp = (const float4*)(W45 + (size_t)((l*NT + t)*300)*64);
  int cbeg = kh*150;
  for (int cc = cbeg; cc < cbeg + 150; ++cc){
    uint2 a2 = *(const uint2*)&As[cc][q*4];
    float4 w = wp[cc*16 + fo];
    float av[4] = {blo(a2.x), bhi(a2.x), blo(a2.y), bhi(a2.y)};
    #pragma unroll
    for (int i = 0; i < 4; ++i){
      acc[i][0] += av[i]*w.x; acc[i][1] += av[i]*w.y; acc[i][2] += av[i]*w.z;
    }
  }
  #pragma unroll
  for (int e = 0; e < 3; ++e)
    #pragma unroll
    for (int i = 0; i < 4; ++i)
      part[kh][fo*3+e][q*4+i] = acc[i][e];
  __syncthreads();

  for (int idx = tid; idx < 32*15; idx += 256){
    int nl2 = idx/15, f2 = idx - nl2*15;
    int n = n0 + nl2;
    if (n < NN){
      float dd = dln[nl2];
      float logd = logf(dd + 1.f);
      float amp = logd*(1.f/LOG17), att = LOG17/logd;
      float g0 = part[0][f2][nl2]    + part[1][f2][nl2];
      float g1 = part[0][15+f2][nl2] + part[1][15+f2][nl2];
      float g2 = part[0][30+f2][nl2] + part[1][30+f2][nl2];
      size_t zi = (size_t)n*75 + t*15 + f2;
      z[zi] = z[zi] + g0 + amp*g1 + att*g2 + postb[(l*NT+t)*15 + f2];
    }
  }
}

// ------ mixing lin: out2 = z @ linW + linb; fused BN partial sums (atomics)
__global__ __launch_bounds__(256) void k_lin(const float* __restrict__ z,
    const float* __restrict__ linW, const float* __restrict__ linb,
    float* __restrict__ out2, float* __restrict__ bnS1, int l){
  __shared__ float zs[75][68];
  __shared__ float lw[75][80];
  int tid = threadIdx.x;
  int n0 = blockIdx.x*64;
  for (int idx = tid; idx < 64*75; idx += 256){
    int i = idx/75, c = idx - i*75;
    zs[c][i] = (n0 + i < NN) ? z[(size_t)n0*75 + idx] : 0.f;
  }
  for (int idx = tid; idx < 75*80; idx += 256){
    int c = idx/80, o = idx - c*80;
    lw[c][o] = (o < 75) ? linW[(size_t)l*5625 + c*75 + o] : 0.f;
  }
  __syncthreads();
  int og = tid >> 4, n4 = tid & 15;
  int o0 = og*5;
  float acc[4][5];
  #pragma unroll
  for (int i = 0; i < 4; ++i)
    #pragma unroll
    for (int k = 0; k < 5; ++k) acc[i][k] = 0.f;
  for (int c = 0; c < 75; ++c){
    float4 a = *reinterpret_cast<const float4*>(&zs[c][n4*4]);
    float av[4] = {a.x, a.y, a.z, a.w};
    float wv[5];
    #pragma unroll
    for (int k = 0; k < 5; ++k) wv[k] = lw[c][o0 + k];
    #pragma unroll
    for (int i = 0; i < 4; ++i)
      #pragma unroll
      for (int k = 0; k < 5; ++k) acc[i][k] += av[i]*wv[k];
  }
  float s1p[5], s2p[5];
  #pragma unroll
  for (int k = 0; k < 5; ++k){ s1p[k] = 0.f; s2p[k] = 0.f; }
  #pragma unroll
  for (int i = 0; i < 4; ++i){
    int n = n0 + n4*4 + i;
    if (n >= NN) continue;
    #pragma unroll
    for (int k = 0; k < 5; ++k){
      int o = o0 + k;
      if (o < 75){
        float v = acc[i][k] + linb[l*75 + o];
        out2[(size_t)n*75 + o] = v;
        s1p[k] += v; s2p[k] += v*v;
      }
    }
  }
  __syncthreads();
  float* red = &zs[0][0];          // [75][16] s1, then [75][16] s2
  #pragma unroll
  for (int k = 0; k < 5; ++k){
    int o = o0 + k;
    if (o < 75){ red[o*16 + n4] = s1p[k]; red[1200 + o*16 + n4] = s2p[k]; }
  }
  __syncthreads();
  if (tid < 75){
    float a1 = 0.f, a2 = 0.f;
    #pragma unroll
    for (int j = 0; j < 16; ++j){ a1 += red[tid*16 + j]; a2 += red[1200 + tid*16 + j]; }
    atomicAdd(&bnS1[tid], a1);
    atomicAdd(&bnS1[80 + tid], a2);
  }
}

// -------------------------------- final BN+ReLU fused with global_add_pool
__global__ __launch_bounds__(256) void k_bnpool(const float* __restrict__ out2,
    const float* __restrict__ bnSp, const float* __restrict__ sc,
    const float* __restrict__ bb, const int* __restrict__ batch,
    float* __restrict__ pooled){
  int i = blockIdx.x*256 + threadIdx.x;
  if (i >= NN*75) return;
  int n = i / 75, f = i - n*75;
  float mu = bnSp[f] * (1.f/NN);
  float var = bnSp[80 + f] * (1.f/NN) - mu*mu;
  float v = fmaxf((out2[i] - mu) / sqrtf(var + 1e-5f) * sc[f] + bb[f], 0.f);
  atomicAdd(&pooled[batch[n]*75 + f], v);
}

__global__ __launch_bounds__(256) void k_head(const float* __restrict__ pooled,
    const float* __restrict__ W1, const float* __restrict__ b1,
    const float* __restrict__ W2, const float* __restrict__ b2,
    const float* __restrict__ W3, const float* __restrict__ b3,
    float* __restrict__ out){
  __shared__ float pl[64*75];
  __shared__ float w1[75*50];
  __shared__ float z1[64*50];
  __shared__ float w2[50*25];
  __shared__ float z2[64*25];
  __shared__ float w3[25];
  __shared__ float bb1[50], bb2[25];
  int tid = threadIdx.x;
  for (int i = tid; i < 64*75; i += 256) pl[i] = pooled[i];
  for (int i = tid; i < 75*50; i += 256) w1[i] = W1[i];
  for (int i = tid; i < 50*25; i += 256) w2[i] = W2[i];
  if (tid < 25) w3[tid] = W3[tid];
  if (tid < 50) bb1[tid] = b1[tid];
  if (tid < 25) bb2[tid] = b2[tid];
  __syncthreads();
  for (int o = tid; o < 64*50; o += 256){
    int g = o / 50, j = o - g*50;
    float acc = bb1[j];
    for (int c = 0; c < 75; ++c) acc += pl[g*75 + c] * w1[c*50 + j];
    z1[o] = fmaxf(acc, 0.f);
  }
  __syncthreads();
  for (int o = tid; o < 64*25; o += 256){
    int g = o / 25, j = o - g*25;
    float acc = bb2[j];
    for (int c = 0; c < 50; ++c) acc += z1[g*50 + c] * w2[c*25 + j];
    z2[o] = fmaxf(acc, 0.f);
  }
  __syncthreads();
  if (tid < 64){
    float acc = b3[0];
    for (int c = 0; c < 25; ++c) acc += z2[tid*25 + c] * w3[c];
    out[tid] = acc;
  }
}

// ---------------------------------------------------------------- launcher
extern "C" void kernel_launch(void* const* d_in, const int* in_sizes, int n_in,
                              void* d_out, int out_size, void* d_ws, size_t ws_size,
                              hipStream_t stream){
  const float* x     = (const float*)d_in[0];
  const int*   ei    = (const int*)  d_in[1];
  const int*   batch = (const int*)  d_in[2];
  const float* plW   = (const float*)d_in[3];
  const float* plb   = (const float*)d_in[4];
  const float* preW  = (const float*)d_in[5];
  const float* preb  = (const float*)d_in[6];
  const float* postW = (const float*)d_in[7];
  const float* postb = (const float*)d_in[8];
  const float* linW  = (const float*)d_in[9];
  const float* linb  = (const float*)d_in[10];
  const float* bns   = (const float*)d_in[11];
  const float* bnb   = (const float*)d_in[12];
  const float* W1    = (const float*)d_in[13];
  const float* b1    = (const float*)d_in[14];
  const float* W2    = (const float*)d_in[15];
  const float* b2    = (const float*)d_in[16];
  const float* W3    = (const float*)d_in[17];
  const float* b3    = (const float*)d_in[18];
  float* out = (float*)d_out;

  // workspace layout (~65.2 MB)
  float* h0    = (float*)d_ws;                     // 750000
  float* out2v = h0 + 750000;                      // 750000
  float* zv    = out2v + 750000;                   // 750000
  float* baseb = zv + 750000;                      // NN*376 f32
  float* Wcat  = baseb + (size_t)NN*376;           // 4*75*896
  float* W45   = Wcat + NL*75*WCN;                 // 4*5*300*64
  float* pooled= W45 + NL*NT*300*64;               // 4800
  float* bnS   = pooled + 4800;                    // 4*160
  unsigned short* out1b = (unsigned short*)(bnS + NL*160);  // NN*384
  unsigned short* aggb  = out1b + (size_t)NN*ROWB;          // NN*1504
  int* cnt = (int*)(aggb + (size_t)NN*1504);
  int* off = cnt + NN;
  int* cur = off + NN + 1;
  int* csr = cur + NN;

  hipMemsetAsync(cnt, 0, NN*sizeof(int), stream);
  hipMemsetAsync(bnS, 0, NL*160*sizeof(float), stream);
  hipMemsetAsync(pooled, 0, 4800*sizeof(float), stream);
  hipMemsetAsync(out1b, 0, (size_t)NN*ROWB*sizeof(unsigned short), stream);
  k_init_h<<<(NN*NF + 255)/256, 256, 0, stream>>>(x, plW, plb, h0);
  k_count<<<(NE + 255)/256, 256, 0, stream>>>(ei, cnt);
  k_scan<<<1, 1024, 0, stream>>>(cnt, off, cur);
  k_scatter<<<(NE + 255)/256, 256, 0, stream>>>(ei, cur, csr);
  k_buildWcat<<<(NL*75*WCN + 255)/256, 256, 0, stream>>>(preW, postW, Wcat);
  k_buildW45<<<(NL*NT*300*64 + 255)/256, 256, 0, stream>>>(postW, W45);

  const int NTILE = (NN + 31)/32;   // 313

  for (int l = 0; l < NL; ++l){
    const float* src = (l == 0) ? h0 : out2v;
    const float* bnSp = bnS + (l > 0 ? (l-1)*160 : 0);
    const float* sc = bns + (l > 0 ? (l-1)*75 : 0);
    const float* bb = bnb + (l > 0 ? (l-1)*75 : 0);
    k_gemm1<<<157*7, 256, 0, stream>>>(src, Wcat, preb, bnSp, sc, bb, (l > 0),
                                       out1b, baseb, zv, l);
    k_gather<<<(NN*64)/256, 256, 0, stream>>>(out1b, baseb, off, csr, aggb);
    k_post<<<NT*NTILE, 256, 0, stream>>>(aggb, zv, off, W45, postb, l);
    k_lin<<<157, 256, 0, stream>>>(zv, linW, linb, out2v, bnS + l*160, l);
  }

  k_bnpool<<<(NN*NF + 255)/256, 256, 0, stream>>>(out2v, bnS + 3*160,
                                                  bns + 3*75, bnb + 3*75, batch, pooled);
  k_head<<<1, 256, 0, stream>>>(pooled, W1, b1, W2, b2, W3, b3, out);
}

// Round 10
// 771.804 us; speedup vs baseline: 1.6534x; 1.0311x over previous
//
#include <hip/hip_runtime.h>

#define NN 10000
#define NE 160000
#define NG 64
#define NT 5
#define NF 75
#define NL 4
#define LOG17 2.8332133f  /* log(17.0) */
#define ROWB 384          /* bf16 B row stride (375 used, pads zeroed once) */
#define WCN 896           /* Wcat cols: B 0..374 | base 384..758 | y0 768..842 | pad */

__device__ __forceinline__ unsigned short f2bf(float x){
  unsigned u = __float_as_uint(x);
  unsigned r = (u + 0x7FFFu + ((u >> 16) & 1u)) >> 16;
  return (unsigned short)r;
}
__device__ __forceinline__ float blo(unsigned u){ return __uint_as_float(u << 16); }
__device__ __forceinline__ float bhi(unsigned u){ return __uint_as_float(u & 0xFFFF0000u); }

// ---------------------------------------------------------------- setup
__global__ __launch_bounds__(256) void k_init_h(const float* __restrict__ x,
    const float* __restrict__ W, const float* __restrict__ b, float* __restrict__ h){
  int i = blockIdx.x*256 + threadIdx.x;
  if (i >= NN*NF) return;
  int n = i / NF, f = i - n*NF;
  h[i] = x[2*n]*W[f] + x[2*n+1]*W[NF+f] + b[f];
}

__global__ __launch_bounds__(256) void k_count(const int* __restrict__ ei, int* __restrict__ cnt){
  int e = blockIdx.x*256 + threadIdx.x;
  if (e < NE) atomicAdd(&cnt[ei[NE + e]], 1);   // row 1 = dst
}

__global__ __launch_bounds__(1024) void k_scan(const int* __restrict__ cnt,
    int* __restrict__ off, int* __restrict__ cur){
  __shared__ int buf[1024];
  __shared__ int carry;
  int tid = threadIdx.x;
  if (tid == 0) carry = 0;
  __syncthreads();
  for (int base = 0; base < NN; base += 1024){
    int i = base + tid;
    int v = (i < NN) ? cnt[i] : 0;
    buf[tid] = v;
    __syncthreads();
    for (int d = 1; d < 1024; d <<= 1){
      int t = (tid >= d) ? buf[tid - d] : 0;
      __syncthreads();
      buf[tid] += t;
      __syncthreads();
    }
    int c = carry;
    if (i < NN){ int ex = c + buf[tid] - v; off[i] = ex; cur[i] = ex; }
    int tot = buf[1023];
    __syncthreads();
    if (tid == 0) carry = c + tot;
    __syncthreads();
  }
  if (tid == 0) off[NN] = NE;
}

__global__ __launch_bounds__(256) void k_scatter(const int* __restrict__ ei,
    int* __restrict__ cur, int* __restrict__ csr){
  int e = blockIdx.x*256 + threadIdx.x;
  if (e < NE){
    int d = ei[NE + e];
    int p = atomicAdd(&cur[d], 1);
    csr[p] = ei[e];   // src node
  }
}

// Wcat[l][75][896]
__global__ __launch_bounds__(256) void k_buildWcat(const float* __restrict__ preW,
    const float* __restrict__ postW, float* __restrict__ Wcat){
  int idx = blockIdx.x*256 + threadIdx.x;
  if (idx >= NL*75*WCN) return;
  int l = idx / (75*WCN);
  int rem = idx - l*75*WCN;
  int c = rem / WCN, j = rem - c*WCN;
  float v = 0.f;
  if (j < 375){
    int t = j/75, f = j - t*75;
    v = preW[(size_t)((l*NT + t)*150 + 75 + c)*75 + f];
  } else if (j >= 384 && j < 759){
    int jj = j - 384; int t = jj/75, f = jj - t*75;
    v = preW[(size_t)((l*NT + t)*150 + c)*75 + f];
  } else if (j >= 768 && j < 843){
    int jj = j - 768; int t = jj/15, f2 = jj - t*15;
    v = postW[(size_t)((l*NT + t)*975 + c)*15 + f2];
  }
  Wcat[idx] = v;
}

// W45[l][t][300][64] f32: col = 4*(f48/3) + f48%3 ; col%4==3 -> 0
__global__ __launch_bounds__(256) void k_buildW45(const float* __restrict__ postW,
    float* __restrict__ W45){
  int idx = blockIdx.x*256 + threadIdx.x;
  if (idx >= NL*NT*300*64) return;
  int l = idx / (NT*300*64);
  int rem = idx - l*NT*300*64;
  int t = rem / (300*64);
  int rem2 = rem - t*300*64;
  int c = rem2 / 64, col = rem2 - c*64;
  int g3 = col >> 2, e = col & 3;
  float v = 0.f;
  if (e < 3){
    int f48 = g3*3 + e;             // [0,48)
    int g = f48/15, f2 = f48 - g*15;
    if (g < 3)
      v = postW[(size_t)((l*NT + t)*975 + 75 + g*300 + c)*15 + f2];
  }
  W45[idx] = v;
}

// ------ GEMM1: [B(bf16) | base(+preb) | y0] = src(BN?) @ Wcat.  M=10000,K=75
// W read straight from global (L2-hot, 16 lanes/wave share each address);
// LDS holds only As -> high occupancy.
__global__ __launch_bounds__(256) void k_gemm1(const float* __restrict__ src,
    const float* __restrict__ Wcat, const float* __restrict__ preb,
    const float* __restrict__ bnSp, const float* __restrict__ sc,
    const float* __restrict__ bb, int use_bn,
    unsigned short* __restrict__ out1b, float* __restrict__ baseb,
    float* __restrict__ z, int l){
  __shared__ float As[75][68];
  int tid = threadIdx.x;
  int bid = blockIdx.x;
  int nt = bid / 7, jt = bid - nt*7;
  int n0 = nt*64, j0 = jt*128;

  for (int idx = tid; idx < 64*75; idx += 256){
    int i = idx/75, c = idx - i*75;
    float v = (n0 + i < NN) ? src[(size_t)n0*75 + idx] : 0.f;
    if (use_bn){
      float mu = bnSp[c] * (1.f/NN);
      float var = bnSp[80 + c] * (1.f/NN) - mu*mu;
      v = fmaxf((v - mu) / sqrtf(var + 1e-5f) * sc[c] + bb[c], 0.f);
    }
    As[c][i] = v;
  }
  __syncthreads();

  int jj = tid >> 4, n4 = tid & 15;
  const float* wg = Wcat + (size_t)l*75*WCN + j0 + jj*8;
  float acc[4][8];
  #pragma unroll
  for (int i = 0; i < 4; ++i)
    #pragma unroll
    for (int j = 0; j < 8; ++j) acc[i][j] = 0.f;

  #pragma unroll 5
  for (int c = 0; c < 75; ++c){
    float4 a  = *reinterpret_cast<const float4*>(&As[c][n4*4]);
    float4 w0 = *reinterpret_cast<const float4*>(&wg[(size_t)c*WCN]);
    float4 w1 = *reinterpret_cast<const float4*>(&wg[(size_t)c*WCN + 4]);
    float av[4] = {a.x, a.y, a.z, a.w};
    float wv[8] = {w0.x, w0.y, w0.z, w0.w, w1.x, w1.y, w1.z, w1.w};
    #pragma unroll
    for (int i = 0; i < 4; ++i)
      #pragma unroll
      for (int j = 0; j < 8; ++j) acc[i][j] += av[i]*wv[j];
  }

  #pragma unroll
  for (int i = 0; i < 4; ++i){
    int n = n0 + n4*4 + i;
    if (n >= NN) continue;
    #pragma unroll
    for (int j = 0; j < 8; ++j){
      int col = j0 + jj*8 + j;
      float v = acc[i][j];
      if (col < 375){
        out1b[(size_t)n*ROWB + col] = f2bf(v);
      } else if (col >= 384 && col < 759){
        baseb[(size_t)n*376 + (col - 384)] = v + preb[l*375 + (col - 384)];
      } else if (col >= 768 && col < 843){
        z[(size_t)n*75 + (col - 768)] = v;
      }
    }
  }
}

// ---- gather-aggregate: 1 wave / node. lanes 0..46 own 8 feats each (uint4).
// writes agg bf16 [n][4 stats][376]  (mean|mn|mx|sd), base folded in.
__device__ __forceinline__ uint4 pack8(const float* v){
  uint4 r;
  r.x = (unsigned)f2bf(v[0]) | ((unsigned)f2bf(v[1]) << 16);
  r.y = (unsigned)f2bf(v[2]) | ((unsigned)f2bf(v[3]) << 16);
  r.z = (unsigned)f2bf(v[4]) | ((unsigned)f2bf(v[5]) << 16);
  r.w = (unsigned)f2bf(v[6]) | ((unsigned)f2bf(v[7]) << 16);
  return r;
}

__global__ __launch_bounds__(256) void k_gather(
    const unsigned short* __restrict__ out1b, const float* __restrict__ baseb,
    const int* __restrict__ off, const int* __restrict__ csr,
    unsigned short* __restrict__ agg){
  int gid = blockIdx.x*256 + threadIdx.x;
  int n = gid >> 6;
  int lane = gid & 63;
  if (n >= NN || lane >= 47) return;
  int fo = lane*8;
  float s[8], ss[8], mn[8], mx[8];
  #pragma unroll
  for (int j = 0; j < 8; ++j){ s[j]=0.f; ss[j]=0.f; mn[j]=3.4e38f; mx[j]=-3.4e38f; }
  int e0 = off[n], e1 = off[n+1], deg = e1 - e0;

#define STT(v,J){ float _v=(v); s[J]+=_v; ss[J]+=_v*_v; mn[J]=fminf(mn[J],_v); mx[J]=fmaxf(mx[J],_v); }
#define PR(X){ STT(blo((X).x),0) STT(bhi((X).x),1) STT(blo((X).y),2) STT(bhi((X).y),3) \
               STT(blo((X).z),4) STT(bhi((X).z),5) STT(blo((X).w),6) STT(bhi((X).w),7) }
  int k = e0;
  for (; k + 4 <= e1; k += 4){
    uint4 a  = *(const uint4*)(out1b + (size_t)csr[k]  *ROWB + fo);
    uint4 b  = *(const uint4*)(out1b + (size_t)csr[k+1]*ROWB + fo);
    uint4 c  = *(const uint4*)(out1b + (size_t)csr[k+2]*ROWB + fo);
    uint4 d2 = *(const uint4*)(out1b + (size_t)csr[k+3]*ROWB + fo);
    PR(a) PR(b) PR(c) PR(d2)
  }
  for (; k < e1; ++k){
    uint4 a = *(const uint4*)(out1b + (size_t)csr[k]*ROWB + fo);
    PR(a)
  }
#undef PR
#undef STT

  float mean[8], sd[8];
  if (deg > 0){
    float rd = 1.f/(float)deg;
    float4 b0 = *(const float4*)(baseb + (size_t)n*376 + fo);
    float4 b1 = *(const float4*)(baseb + (size_t)n*376 + fo + 4);
    float bs[8] = {b0.x,b0.y,b0.z,b0.w,b1.x,b1.y,b1.z,b1.w};
    #pragma unroll
    for (int j = 0; j < 8; ++j){
      float mb = s[j]*rd;
      float var = ss[j]*rd - mb*mb;
      mean[j] = bs[j] + mb;
      sd[j]   = sqrtf(fmaxf(var, 0.f) + 1e-5f);
      mn[j]   = bs[j] + mn[j];
      mx[j]   = bs[j] + mx[j];
    }
  } else {
    #pragma unroll
    for (int j = 0; j < 8; ++j){ mean[j]=0.f; mn[j]=0.f; mx[j]=0.f; sd[j]=sqrtf(1e-5f); }
  }
  unsigned short* ap = agg + (size_t)n*1504 + fo;
  *(uint4*)(ap)        = pack8(mean);
  *(uint4*)(ap + 376)  = pack8(mn);
  *(uint4*)(ap + 752)  = pack8(mx);
  *(uint4*)(ap + 1128) = pack8(sd);
}

// ---- post: one (32-node tile, tower) per block. 256 thr = 8 quads x 16 fo x 2 kh.
// Each thread: 4 nodes x 3 cols -> 12 FMA per 16B W45 load. A in LDS as bf16.
__global__ __launch_bounds__(256) void k_post(
    const unsigned short* __restrict__ agg, float* __restrict__ z,
    const int* __restrict__ off,
    const float* __restrict__ W45, const float* __restrict__ postb, int l){
  __shared__ unsigned short As[300][40];   // bf16; row=K idx, col=node (32+8 pad)
  __shared__ float part[2][48][33];
  __shared__ float dln[32];
  int tid = threadIdx.x;
  int bid = blockIdx.x;
  const int NTILE = (NN + 31)/32;          // 313
  int t = bid / NTILE;                     // tower-major: share W45 slice in L2
  int nt = bid - t*NTILE;
  int n0 = nt*32;
  if (tid < 32){
    int n = n0 + tid;
    int dd = (n < NN) ? (off[n+1] - off[n]) : 1;
    dln[tid] = (float)(dd > 0 ? dd : 1);
  }
  // stage: coalesced along c within each node's tower-t slice
  for (int idx = tid; idx < 32*300; idx += 256){
    int nl = idx/300, c = idx - nl*300;
    int n = n0 + nl;
    unsigned short raw = 0;
    if (n < NN){
      int st = c/75, u = c - st*75;
      raw = agg[(size_t)n*1504 + st*376 + t*75 + u];
    }
    As[c][nl] = raw;
  }
  __syncthreads();

  int q  = tid & 7;                 // node quad: nodes q*4 .. q*4+3
  int fo = (tid >> 3) & 15;         // 3 output cols
  int kh = tid >> 7;                // K half
  float acc[4][3];
  #pragma unroll
  for (int i = 0; i < 4; ++i){ acc[i][0]=0.f; acc[i][1]=0.f; acc[i][2]=0.f; }
  const float4* wp = (const float4*)(W45 + (size_t)((l*NT + t)*300)*64);
  int cbeg = kh*150;
  for (int cc = cbeg; cc < cbeg + 150; ++cc){
    uint2 a2 = *(const uint2*)&As[cc][q*4];
    float4 w = wp[cc*16 + fo];
    float av[4] = {blo(a2.x), bhi(a2.x), blo(a2.y), bhi(a2.y)};
    #pragma unroll
    for (int i = 0; i < 4; ++i){
      acc[i][0] += av[i]*w.x; acc[i][1] += av[i]*w.y; acc[i][2] += av[i]*w.z;
    }
  }
  #pragma unroll
  for (int e = 0; e < 3; ++e)
    #pragma unroll
    for (int i = 0; i < 4; ++i)
      part[kh][fo*3+e][q*4+i] = acc[i][e];
  __syncthreads();

  for (int idx = tid; idx < 32*15; idx += 256){
    int nl2 = idx/15, f2 = idx - nl2*15;
    int n = n0 + nl2;
    if (n < NN){
      float dd = dln[nl2];
      float logd = logf(dd + 1.f);
      float amp = logd*(1.f/LOG17), att = LOG17/logd;
      float g0 = part[0][f2][nl2]    + part[1][f2][nl2];
      float g1 = part[0][15+f2][nl2] + part[1][15+f2][nl2];
      float g2 = part[0][30+f2][nl2] + part[1][30+f2][nl2];
      size_t zi = (size_t)n*75 + t*15 + f2;
      z[zi] = z[zi] + g0 + amp*g1 + att*g2 + postb[(l*NT+t)*15 + f2];
    }
  }
}

// ------ mixing lin: out2 = z @ linW + linb; fused BN partial sums (atomics)
__global__ __launch_bounds__(256) void k_lin(const float* __restrict__ z,
    const float* __restrict__ linW, const float* __restrict__ linb,
    float* __restrict__ out2, float* __restrict__ bnS1, int l){
  __shared__ float zs[75][68];
  __shared__ float lw[75][80];
  int tid = threadIdx.x;
  int n0 = blockIdx.x*64;
  for (int idx = tid; idx < 64*75; idx += 256){
    int i = idx/75, c = idx - i*75;
    zs[c][i] = (n0 + i < NN) ? z[(size_t)n0*75 + idx] : 0.f;
  }
  for (int idx = tid; idx < 75*80; idx += 256){
    int c = idx/80, o = idx - c*80;
    lw[c][o] = (o < 75) ? linW[(size_t)l*5625 + c*75 + o] : 0.f;
  }
  __syncthreads();
  int og = tid >> 4, n4 = tid & 15;
  int o0 = og*5;
  float acc[4][5];
  #pragma unroll
  for (int i = 0; i < 4; ++i)
    #pragma unroll
    for (int k = 0; k < 5; ++k) acc[i][k] = 0.f;
  for (int c = 0; c < 75; ++c){
    float4 a = *reinterpret_cast<const float4*>(&zs[c][n4*4]);
    float av[4] = {a.x, a.y, a.z, a.w};
    float wv[5];
    #pragma unroll
    for (int k = 0; k < 5; ++k) wv[k] = lw[c][o0 + k];
    #pragma unroll
    for (int i = 0; i < 4; ++i)
      #pragma unroll
      for (int k = 0; k < 5; ++k) acc[i][k] += av[i]*wv[k];
  }
  float s1p[5], s2p[5];
  #pragma unroll
  for (int k = 0; k < 5; ++k){ s1p[k] = 0.f; s2p[k] = 0.f; }
  #pragma unroll
  for (int i = 0; i < 4; ++i){
    int n = n0 + n4*4 + i;
    if (n >= NN) continue;
    #pragma unroll
    for (int k = 0; k < 5; ++k){
      int o = o0 + k;
      if (o < 75){
        float v = acc[i][k] + linb[l*75 + o];
        out2[(size_t)n*75 + o] = v;
        s1p[k] += v; s2p[k] += v*v;
      }
    }
  }
  __syncthreads();
  float* red = &zs[0][0];          // [75][16] s1, then [75][16] s2
  #pragma unroll
  for (int k = 0; k < 5; ++k){
    int o = o0 + k;
    if (o < 75){ red[o*16 + n4] = s1p[k]; red[1200 + o*16 + n4] = s2p[k]; }
  }
  __syncthreads();
  if (tid < 75){
    float a1 = 0.f, a2 = 0.f;
    #pragma unroll
    for (int j = 0; j < 16; ++j){ a1 += red[tid*16 + j]; a2 += red[1200 + tid*16 + j]; }
    atomicAdd(&bnS1[tid], a1);
    atomicAdd(&bnS1[80 + tid], a2);
  }
}

// -------------------------------- final BN+ReLU fused with global_add_pool
__global__ __launch_bounds__(256) void k_bnpool(const float* __restrict__ out2,
    const float* __restrict__ bnSp, const float* __restrict__ sc,
    const float* __restrict__ bb, const int* __restrict__ batch,
    float* __restrict__ pooled){
  int i = blockIdx.x*256 + threadIdx.x;
  if (i >= NN*75) return;
  int n = i / 75, f = i - n*75;
  float mu = bnSp[f] * (1.f/NN);
  float var = bnSp[80 + f] * (1.f/NN) - mu*mu;
  float v = fmaxf((out2[i] - mu) / sqrtf(var + 1e-5f) * sc[f] + bb[f], 0.f);
  atomicAdd(&pooled[batch[n]*75 + f], v);
}

__global__ __launch_bounds__(256) void k_head(const float* __restrict__ pooled,
    const float* __restrict__ W1, const float* __restrict__ b1,
    const float* __restrict__ W2, const float* __restrict__ b2,
    const float* __restrict__ W3, const float* __restrict__ b3,
    float* __restrict__ out){
  __shared__ float pl[64*75];
  __shared__ float w1[75*50];
  __shared__ float z1[64*50];
  __shared__ float w2[50*25];
  __shared__ float z2[64*25];
  __shared__ float w3[25];
  __shared__ float bb1[50], bb2[25];
  int tid = threadIdx.x;
  for (int i = tid; i < 64*75; i += 256) pl[i] = pooled[i];
  for (int i = tid; i < 75*50; i += 256) w1[i] = W1[i];
  for (int i = tid; i < 50*25; i += 256) w2[i] = W2[i];
  if (tid < 25) w3[tid] = W3[tid];
  if (tid < 50) bb1[tid] = b1[tid];
  if (tid < 25) bb2[tid] = b2[tid];
  __syncthreads();
  for (int o = tid; o < 64*50; o += 256){
    int g = o / 50, j = o - g*50;
    float acc = bb1[j];
    for (int c = 0; c < 75; ++c) acc += pl[g*75 + c] * w1[c*50 + j];
    z1[o] = fmaxf(acc, 0.f);
  }
  __syncthreads();
  for (int o = tid; o < 64*25; o += 256){
    int g = o / 25, j = o - g*25;
    float acc = bb2[j];
    for (int c = 0; c < 50; ++c) acc += z1[g*50 + c] * w2[c*25 + j];
    z2[o] = fmaxf(acc, 0.f);
  }
  __syncthreads();
  if (tid < 64){
    float acc = b3[0];
    for (int c = 0; c < 25; ++c) acc += z2[tid*25 + c] * w3[c];
    out[tid] = acc;
  }
}

// ---------------------------------------------------------------- launcher
extern "C" void kernel_launch(void* const* d_in, const int* in_sizes, int n_in,
                              void* d_out, int out_size, void* d_ws, size_t ws_size,
                              hipStream_t stream){
  const float* x     = (const float*)d_in[0];
  const int*   ei    = (const int*)  d_in[1];
  const int*   batch = (const int*)  d_in[2];
  const float* plW   = (const float*)d_in[3];
  const float* plb   = (const float*)d_in[4];
  const float* preW  = (const float*)d_in[5];
  const float* preb  = (const float*)d_in[6];
  const float* postW = (const float*)d_in[7];
  const float* postb = (const float*)d_in[8];
  const float* linW  = (const float*)d_in[9];
  const float* linb  = (const float*)d_in[10];
  const float* bns   = (const float*)d_in[11];
  const float* bnb   = (const float*)d_in[12];
  const float* W1    = (const float*)d_in[13];
  const float* b1    = (const float*)d_in[14];
  const float* W2    = (const float*)d_in[15];
  const float* b2    = (const float*)d_in[16];
  const float* W3    = (const float*)d_in[17];
  const float* b3    = (const float*)d_in[18];
  float* out = (float*)d_out;

  // workspace layout (~65.2 MB)
  float* h0    = (float*)d_ws;                     // 750000
  float* out2v = h0 + 750000;                      // 750000
  float* zv    = out2v + 750000;                   // 750000
  float* baseb = zv + 750000;                      // NN*376 f32
  float* Wcat  = baseb + (size_t)NN*376;           // 4*75*896
  float* W45   = Wcat + NL*75*WCN;                 // 4*5*300*64
  float* pooled= W45 + NL*NT*300*64;               // 4800
  float* bnS   = pooled + 4800;                    // 4*160
  unsigned short* out1b = (unsigned short*)(bnS + NL*160);  // NN*384
  unsigned short* aggb  = out1b + (size_t)NN*ROWB;          // NN*1504
  int* cnt = (int*)(aggb + (size_t)NN*1504);
  int* off = cnt + NN;
  int* cur = off + NN + 1;
  int* csr = cur + NN;

  hipMemsetAsync(cnt, 0, NN*sizeof(int), stream);
  hipMemsetAsync(bnS, 0, NL*160*sizeof(float), stream);
  hipMemsetAsync(pooled, 0, 4800*sizeof(float), stream);
  hipMemsetAsync(out1b, 0, (size_t)NN*ROWB*sizeof(unsigned short), stream);
  k_init_h<<<(NN*NF + 255)/256, 256, 0, stream>>>(x, plW, plb, h0);
  k_count<<<(NE + 255)/256, 256, 0, stream>>>(ei, cnt);
  k_scan<<<1, 1024, 0, stream>>>(cnt, off, cur);
  k_scatter<<<(NE + 255)/256, 256, 0, stream>>>(ei, cur, csr);
  k_buildWcat<<<(NL*75*WCN + 255)/256, 256, 0, stream>>>(preW, postW, Wcat);
  k_buildW45<<<(NL*NT*300*64 + 255)/256, 256, 0, stream>>>(postW, W45);

  const int NTILE = (NN + 31)/32;   // 313

  for (int l = 0; l < NL; ++l){
    const float* src = (l == 0) ? h0 : out2v;
    const float* bnSp = bnS + (l > 0 ? (l-1)*160 : 0);
    const float* sc = bns + (l > 0 ? (l-1)*75 : 0);
    const float* bb = bnb + (l > 0 ? (l-1)*75 : 0);
    k_gemm1<<<157*7, 256, 0, stream>>>(src, Wcat, preb, bnSp, sc, bb, (l > 0),
                                       out1b, baseb, zv, l);
    k_gather<<<(NN*64)/256, 256, 0, stream>>>(out1b, baseb, off, csr, aggb);
    k_post<<<NT*NTILE, 256, 0, stream>>>(aggb, zv, off, W45, postb, l);
    k_lin<<<157, 256, 0, stream>>>(zv, linW, linb, out2v, bnS + l*160, l);
  }

  k_bnpool<<<(NN*NF + 255)/256, 256, 0, stream>>>(out2v, bnS + 3*160,
                                                  bns + 3*75, bnb + 3*75, batch, pooled);
  k_head<<<1, 256, 0, stream>>>(pooled, W1, b1, W2, b2, W3, b3, out);
}